// Round 5
// baseline (314.525 us; speedup 1.0000x reference)
//
#include <hip/hip_runtime.h>
#include <hip/hip_bf16.h>
#include <stdint.h>

#define S_LEN 2048
#define H_DIM 2048
#define NHEADS 16
#define KVHEADS 4
#define HEAD_DIM 128
#define KV_DIM 512       // KVHEADS * HEAD_DIM
#define NTOK 4096        // B * S
#define NQKV 3072        // H_DIM + 2*KV_DIM

typedef __bf16 bf16_t;
typedef __bf16 bf16x8 __attribute__((ext_vector_type(8)));
typedef __bf16 bf16x4 __attribute__((ext_vector_type(4)));
typedef float f32x4 __attribute__((ext_vector_type(4)));

__device__ __forceinline__ f32x4 mfma16x16x32(bf16x8 a, bf16x8 b, f32x4 c) {
    return __builtin_amdgcn_mfma_f32_16x16x32_bf16(a, b, c, 0, 0, 0);
}

// async global->LDS, 16B per lane. LDS dest = wave-uniform base + lane*16;
// global address may be fully per-lane (scatter side is global).
__device__ __forceinline__ void gload_lds16(const bf16_t* g, bf16_t* l) {
    __builtin_amdgcn_global_load_lds(
        (__attribute__((address_space(1))) uint32_t*)(uintptr_t)g,
        (__attribute__((address_space(3))) uint32_t*)l, 16, 0, 0);
}

// Fused fp32->bf16 convert of all 5 tensors in one launch (8 elems/thread).
// Wq/Wk rows are PERMUTED on the fly: phys row j = head*128 + 64s + 16a + c
// takes logical row head*128 + 64(a&1) + 32s + 16(a>>1) + c. This places each
// RoPE pair (d, d+64) into the same epilogue thread of gemm_qkv (ni=2P lo,
// ni=2P+1 hi). Q/K remain dim-permuted in memory; QK^T is invariant since
// the same bijection is applied to both operands, and V/O/gemm_out never see
// the permuted axis.
#define N_X  (NTOK * H_DIM)     // 8388608
#define N_WQ (H_DIM * H_DIM)    // 4194304
#define N_WK (KV_DIM * H_DIM)   // 1048576
__global__ __launch_bounds__(256) void cvt_all(const float* __restrict__ X,
                                               const float* __restrict__ Wq,
                                               const float* __restrict__ Wk,
                                               const float* __restrict__ Wv,
                                               const float* __restrict__ Wo,
                                               bf16_t* __restrict__ Xb,
                                               bf16_t* __restrict__ Wqb,
                                               bf16_t* __restrict__ Wkb,
                                               bf16_t* __restrict__ Wvb,
                                               bf16_t* __restrict__ Wob) {
    long i = (long)(blockIdx.x * 256 + threadIdx.x) * 8;
    const float* src;
    bf16_t* dst;
    bool perm = false;
    if (i < N_X)                       { src = X;  dst = Xb; }
    else if ((i -= N_X) < N_WQ)        { src = Wq; dst = Wqb; perm = true; }
    else if ((i -= N_WQ) < N_WK)       { src = Wk; dst = Wkb; perm = true; }
    else if ((i -= N_WK) < N_WK)       { src = Wv; dst = Wvb; }
    else      { i -= N_WK;               src = Wo; dst = Wob; }
    long isrc = i;
    if (perm) {
        const long jrow = i >> 11;          // dst row (2048 elems/row)
        const int  o    = (int)(i & 2047);
        const int  a    = (int)(jrow >> 4) & 3;
        const int  sh   = (int)(jrow >> 6) & 1;
        const long srow = (jrow & ~127L) | ((long)(a & 1) << 6) |
                          ((long)sh << 5) | ((long)(a >> 1) << 4) | (jrow & 15);
        isrc = srow * 2048 + o;
    }
    const float4 va = *(const float4*)(src + isrc);
    const float4 vb = *(const float4*)(src + isrc + 4);
    bf16x8 ov;
    ov[0] = (bf16_t)va.x; ov[1] = (bf16_t)va.y; ov[2] = (bf16_t)va.z; ov[3] = (bf16_t)va.w;
    ov[4] = (bf16_t)vb.x; ov[5] = (bf16_t)vb.y; ov[6] = (bf16_t)vb.z; ov[7] = (bf16_t)vb.w;
    *(bf16x8*)(dst + i) = ov;
}

// ---- shared GEMM main loop (m97 structure), used by both GEMM kernels ----
// computes acc[4][4] for this thread's 64x64 wave tile at (m0+wm, n0+wn)
#define GEMM_BODY(A_, W_, K_)                                                  \
    __shared__ alignas(16) bf16_t As[128 * 32];                                \
    __shared__ alignas(16) bf16_t Bs[128 * 32];                                \
    const int tid  = threadIdx.x;                                              \
    const int wave = tid >> 6;                                                 \
    const int lane = tid & 63;                                                 \
    const int col  = lane & 15;                                                \
    const int quad = lane >> 4;                                                \
    const int m0 = blockIdx.y * 128;                                           \
    const int n0 = blockIdx.x * 128;                                           \
    const int wm = (wave >> 1) * 64;                                           \
    const int wn = (wave & 1) * 64;                                            \
    const int r0 = tid >> 2;                                                   \
    const int kk = (tid & 3) * 8;                                              \
    const bf16_t* a0 = (A_) + (size_t)(m0 + r0) * (K_) + kk;                   \
    const bf16_t* a1 = a0 + (size_t)64 * (K_);                                 \
    const bf16_t* b0 = (W_) + (size_t)(n0 + r0) * (K_) + kk;                   \
    const bf16_t* b1 = b0 + (size_t)64 * (K_);                                 \
    bf16_t* lA0 = As + tid * 8;                                                \
    bf16_t* lA1 = As + 2048 + tid * 8;                                         \
    bf16_t* lB0 = Bs + tid * 8;                                                \
    bf16_t* lB1 = Bs + 2048 + tid * 8;                                         \
    f32x4 acc[4][4];                                                           \
    _Pragma("unroll") for (int mi = 0; mi < 4; ++mi)                           \
        _Pragma("unroll") for (int ni = 0; ni < 4; ++ni)                       \
            acc[mi][ni] = (f32x4){0.f, 0.f, 0.f, 0.f};                         \
    for (int k0 = 0; k0 < (K_); k0 += 32) {                                    \
        __syncthreads();                                                       \
        gload_lds16(a0 + k0, lA0);                                             \
        gload_lds16(a1 + k0, lA1);                                             \
        gload_lds16(b0 + k0, lB0);                                             \
        gload_lds16(b1 + k0, lB1);                                             \
        __syncthreads();                                                       \
        bf16x8 av[4], bv[4];                                                   \
        _Pragma("unroll") for (int i = 0; i < 4; ++i) {                        \
            av[i] = *(const bf16x8*)(As + (wm + i * 16 + col) * 32 + quad * 8);\
            bv[i] = *(const bf16x8*)(Bs + (wn + i * 16 + col) * 32 + quad * 8);\
        }                                                                      \
        _Pragma("unroll") for (int mi = 0; mi < 4; ++mi)                       \
            _Pragma("unroll") for (int ni = 0; ni < 4; ++ni)                   \
                acc[mi][ni] = mfma16x16x32(av[mi], bv[ni], acc[mi][ni]);       \
    }

#define QSCALE_LOG2E 0.12753102813264324f  // (1/sqrt(128)) * log2(e)

// Fused QKV projection + RoPE epilogue. C row-major views into qbuf
// [M][2048] (n<2048), kbuf [M][512] (2048<=n<2560), and V^T layout
// [b][kvh*128+d][s] (n>=2560). Wq/Wk were row-permuted in cvt_all so each
// thread's (ni=2P, ni=2P+1) fragments hold a RoPE pair (logical dims dlo,
// dlo+64 with dlo = 32*s_half + 16P + col); the rotation is applied to the
// fp32 accumulator, Q additionally scaled by scale*log2e so attn uses exp2
// with no per-score multiply (attn overwrites Q with O before gemm_out).
__global__ __launch_bounds__(256) void gemm_qkv(const bf16_t* __restrict__ A,
                                                const bf16_t* __restrict__ W,
                                                const float* __restrict__ cosb,
                                                const float* __restrict__ sinb,
                                                bf16_t* __restrict__ qbuf,
                                                bf16_t* __restrict__ kbuf,
                                                bf16_t* __restrict__ vtbuf) {
    GEMM_BODY(A, W, H_DIM)
    const int ng = n0 + wn;   // 64-aligned; q/k/v boundaries are 64-aligned
    if (ng < H_DIM + KV_DIM) {
        // Q or K: fused RoPE on the fp32 accumulator
        const bool isq   = (ng < H_DIM);
        const int  nrel  = isq ? ng : (ng - H_DIM);
        const int  s_half = (nrel >> 6) & 1;
        bf16_t*    obuf  = isq ? qbuf : kbuf;
        const int  ostr  = isq ? H_DIM : KV_DIM;
        const float qs   = isq ? QSCALE_LOG2E : 1.0f;
#pragma unroll
        for (int mi = 0; mi < 4; ++mi) {
#pragma unroll
            for (int r = 0; r < 4; ++r) {
                const int m   = m0 + wm + mi * 16 + quad * 4 + r;
                const int tok = m & (S_LEN - 1);
                const float* cb = cosb + tok * HEAD_DIM;
                const float* sb = sinb + tok * HEAD_DIM;
#pragma unroll
                for (int P = 0; P < 2; ++P) {
                    const int dlo = s_half * 32 + P * 16 + col;
                    const float lo = acc[mi][2 * P][r];
                    const float hi = acc[mi][2 * P + 1][r];
                    const float c0 = cb[dlo],      s0 = sb[dlo];
                    const float c1 = cb[dlo + 64], s1 = sb[dlo + 64];
                    const float o_lo = (lo * c0 - hi * s0) * qs;
                    const float o_hi = (hi * c1 + lo * s1) * qs;
                    obuf[(size_t)m * ostr + nrel + (2 * P) * 16 + col] =
                        (bf16_t)o_lo;
                    obuf[(size_t)m * ostr + nrel + (2 * P + 1) * 16 + col] =
                        (bf16_t)o_hi;
                }
            }
        }
    } else {
#pragma unroll
        for (int mi = 0; mi < 4; ++mi) {
            const int m = m0 + wm + mi * 16 + quad * 4;
#pragma unroll
            for (int ni = 0; ni < 4; ++ni) {
                const int nv = ng - (H_DIM + KV_DIM) + ni * 16 + col;
                const size_t off =
                    ((size_t)(m >> 11) * KV_DIM + nv) * S_LEN + (m & (S_LEN - 1));
                bf16x4 o;
#pragma unroll
                for (int r = 0; r < 4; ++r) o[r] = (bf16_t)acc[mi][ni][r];
                *(bf16x4*)(vtbuf + off) = o;
            }
        }
    }
}

// O projection: fp32 output.
__global__ __launch_bounds__(256) void gemm_out(const bf16_t* __restrict__ A,
                                                const bf16_t* __restrict__ W,
                                                float* __restrict__ C) {
    GEMM_BODY(A, W, H_DIM)
#pragma unroll
    for (int mi = 0; mi < 4; ++mi)
#pragma unroll
        for (int ni = 0; ni < 4; ++ni)
#pragma unroll
            for (int r = 0; r < 4; ++r)
                C[(size_t)(m0 + wm + mi * 16 + quad * 4 + r) * H_DIM +
                  n0 + wn + ni * 16 + col] = (float)acc[mi][ni][r];
}

#define NEG_BIG (-1e30f)
#define TJ 64          // kv tile width
#define DEFER_THR 8.0f // defer-max threshold, log2 units (P bounded by 2^8)

// Flash attention, causal, transposed-score form.
// 8-wave (512-thread) blocks: waves 0-3 own q-tile 2i, waves 4-7 own q-tile
// 2i+1 (one GQA head each); both tiles need the SAME nsteps = i/2+1, so all
// 8 waves run uniform barriers while sharing one K/V staging stream.
// Complementary CU pairing: blocks id and id+256 co-locate on a CU under
// round-robin dispatch; i = (b? 63-j : j) makes each CU's two resident
// blocks' durations sum to exactly 33 steps. LDS = 64 KB -> 2 blocks/CU.
// PV is K=32 MFMA with P^T staged through LDS -- but at ZERO extra LDS: the
// current K tile (16 KB = 8 waves x 2 KB) is dead after QK^T, so after a raw
// s_barrier (NOT __syncthreads: must not drain the in-flight vmcnt prefetch)
// each wave reuses its 2 KB slice of Ks[cur] as wave-private P^T scratch.
// Safety: each wave's K ds_reads complete before its last QK^T MFMA issues
// (compiler waitcnts), so barrier => all K reads done => P writes safe;
// sched_barrier(0) fences code motion around the raw barrier. The DMA always
// targets buffer cur^1, P always buffer cur -> no overlap.
// PV operand order mfma(vf, aP): D = O^T, layout O[q=col][d=dt*16+quad*4+r]
// -> alpha/l rescale is broadcast-free (indexed by q=col) and the epilogue
// stores are aligned bf16x4.
// NOTE: Q and K arrive dim-PERMUTED (see cvt_all); QK^T is invariant because
// both operands carry the same bijection on the contraction axis.
__global__ __launch_bounds__(512, 4) void attn_fwd(bf16_t* __restrict__ Q,
                                                   const bf16_t* __restrict__ Kb,
                                                   const bf16_t* __restrict__ Vt) {
    const int id   = blockIdx.x;       // 0..511
    const int jp   = id & 63;
    const int kvh  = (id >> 6) & 3;
    const int b    = id >> 8;
    const int i    = b ? (63 - jp) : jp;   // complementary pairing per CU
    const int tid  = threadIdx.x;
    const int wave = tid >> 6;
    const int lane = tid & 63;
    const int col  = lane & 15;
    const int quad = lane >> 4;
    const int grp  = wave >> 2;        // 0: tile 2i, 1: tile 2i+1
    const int h    = kvh * 4 + (wave & 3);
    const int q0   = (2 * i + grp) * 16;
    const int nsteps = (i >> 1) + 1;
    const int swz  = col & 7;          // read-side swizzle key

    // chunk-swizzled tiles: slot(j,c) = j*16 + (c^(j&7)) for K [64j][16c],
    // slot(d,cj) = d*8 + (cj^(d&7)) for V^T [128d][8cj]; elem addr = slot*8.
    __shared__ alignas(16) bf16_t Ks[2][TJ * HEAD_DIM];    // 16 KB each
    __shared__ alignas(16) bf16_t Vs[2][HEAD_DIM * TJ];    // 16 KB each

    const bf16_t* kbase = Kb + (size_t)(b * S_LEN) * KV_DIM + kvh * HEAD_DIM;
    const bf16_t* vtb   = Vt + (size_t)(b * KVHEADS + kvh) * HEAD_DIM * S_LEN;

    // per-lane global element offsets for the 2 K + 2 V staging DMAs
    int kgoff[2], vgoff[2];
#pragma unroll
    for (int im = 0; im < 2; ++im) {
        const int s = im * 512 + tid;
        const int jr = s >> 4, c = (s & 15) ^ (jr & 7);
        kgoff[im] = jr * KV_DIM + c * 8;
        const int d = s >> 3, cj = (s & 7) ^ (d & 7);
        vgoff[im] = d * S_LEN + cj * 8;
    }
    auto stage = [&](int buf, int j0) {
        const bf16_t* kb = kbase + (size_t)j0 * KV_DIM;
        const bf16_t* vb = vtb + j0;
#pragma unroll
        for (int im = 0; im < 2; ++im) {
            gload_lds16(kb + kgoff[im], &Ks[buf][(im * 512 + wave * 64) * 8]);
            gload_lds16(vb + vgoff[im], &Vs[buf][(im * 512 + wave * 64) * 8]);
        }
    };

    // hoisted fragment LDS byte addrs; tile index goes into imm offsets:
    // K frag (t,jc): kaddr[t] + jc*4096;  V frag (half,dt): vb0/1 + dt*2048
    int kaddr[4];
#pragma unroll
    for (int t = 0; t < 4; ++t)
        kaddr[t] = col * 256 + (((4 * t + quad) ^ swz) << 4);
    const int vb0 = col * 128 + ((quad ^ swz) << 4);
    const int vb1 = col * 128 + (((quad + 4) ^ swz) << 4);
    // P^T scratch offsets within the dead K tile (wave-private 2 KB slice):
    // logical [q=col][j] row-major 128 B/row, XOR-swizzled by (col&7)<<4.
    int pwoff[4];
#pragma unroll
    for (int jc = 0; jc < 4; ++jc)
        pwoff[jc] = wave * 2048 +
                    ((col * 128 + jc * 32 + quad * 8) ^ (swz << 4));
    const int ap0 = wave * 2048 + ((col * 128 + quad * 16) ^ (swz << 4));
    const int ap1 = wave * 2048 + ((col * 128 + 64 + quad * 16) ^ (swz << 4));

// one kv-step with compile-time buffer index BUF (so the +16KiB buffer
// stride folds into ds_read offset immediates -> zero address VALU in loop)
#define ATTN_STEP(JT, BUF)                                                     \
    {                                                                          \
        const int jt_ = (JT);                                                  \
        const bool last_ = (jt_ == nsteps - 1);                                \
        __syncthreads();  /* vmcnt(0) drain: buf BUF staged; prev reads done */\
        if (!last_) stage((BUF) ^ 1, (jt_ + 1) * TJ);                          \
        const char* ksb = (const char*)Ks[(BUF)];                              \
        const char* vsb = (const char*)Vs[(BUF)];                              \
        char* pwb = (char*)Ks[(BUF)];   /* dead after QK^T; P^T scratch */     \
        f32x4 sc[4];                                                           \
        _Pragma("unroll") for (int jc = 0; jc < 4; ++jc)                       \
            sc[jc] = (f32x4){0.f, 0.f, 0.f, 0.f};                              \
        __builtin_amdgcn_s_setprio(1);                                         \
        _Pragma("unroll") for (int t = 0; t < 4; ++t)                          \
            _Pragma("unroll") for (int jc = 0; jc < 4; ++jc)                   \
                sc[jc] = mfma16x16x32(                                         \
                    *(const bf16x8*)(ksb + kaddr[t] + jc * 4096), qf[t],       \
                    sc[jc]);                                                   \
        __builtin_amdgcn_s_setprio(0);                                         \
        if (last_) {                                                           \
            const int j0_ = jt_ * TJ;                                          \
            const int q_ = q0 + col;                                           \
            _Pragma("unroll") for (int jc = 0; jc < 4; ++jc)                   \
                _Pragma("unroll") for (int r = 0; r < 4; ++r) {                \
                    const int j = j0_ + jc * 16 + quad * 4 + r;                \
                    if (j > q_) sc[jc][r] = NEG_BIG;                           \
                }                                                              \
        }                                                                      \
        float mx = sc[0][0];                                                   \
        _Pragma("unroll") for (int jc = 0; jc < 4; ++jc)                       \
            _Pragma("unroll") for (int r = 0; r < 4; ++r)                      \
                mx = fmaxf(mx, sc[jc][r]);                                     \
        /* per-lane partial max is a lower bound of the column max: if no  */  \
        /* lane exceeds m_i+THR, no column max does -> skip reduce+rescale */  \
        if (!__all(mx <= m_i + DEFER_THR)) {                                   \
            mx = fmaxf(mx, __shfl_xor(mx, 16));                                \
            mx = fmaxf(mx, __shfl_xor(mx, 32));                                \
            const float mn = fmaxf(m_i, mx);                                   \
            const float alpha = __builtin_amdgcn_exp2f(m_i - mn);              \
            m_i = mn;                                                          \
            l_i *= alpha;                                                      \
            _Pragma("unroll") for (int dt = 0; dt < 8; ++dt)                   \
                Oacc[dt] *= alpha;  /* O rows are q=col: no broadcast */       \
        }                                                                      \
        float sum = 0.f;                                                       \
        bf16x4 pb[4];                                                          \
        _Pragma("unroll") for (int jc = 0; jc < 4; ++jc)                       \
            _Pragma("unroll") for (int r = 0; r < 4; ++r) {                    \
                const float pe = __builtin_amdgcn_exp2f(sc[jc][r] - m_i);      \
                sum += pe;                                                     \
                pb[jc][r] = (bf16_t)pe;                                        \
            }                                                                  \
        /* barrier: every wave's K-reads are complete; K tile becomes P^T */   \
        __builtin_amdgcn_sched_barrier(0);                                     \
        __builtin_amdgcn_s_barrier();                                          \
        __builtin_amdgcn_sched_barrier(0);                                     \
        _Pragma("unroll") for (int jc = 0; jc < 4; ++jc)                       \
            *(bf16x4*)(pwb + pwoff[jc]) = pb[jc];                              \
        sum += __shfl_xor(sum, 16);                                            \
        sum += __shfl_xor(sum, 32);                                            \
        l_i += sum;                                                            \
        asm volatile("s_waitcnt lgkmcnt(0)" ::: "memory");  /* P visible */    \
        const bf16x8 aP0 = *(const bf16x8*)(pwb + ap0);                        \
        const bf16x8 aP1 = *(const bf16x8*)(pwb + ap1);                        \
        __builtin_amdgcn_s_setprio(1);                                         \
        _Pragma("unroll") for (int dt = 0; dt < 8; ++dt) {                     \
            const bf16x8 vf0 = *(const bf16x8*)(vsb + vb0 + dt * 2048);        \
            const bf16x8 vf1 = *(const bf16x8*)(vsb + vb1 + dt * 2048);        \
            Oacc[dt] = mfma16x16x32(vf1, aP1,                                  \
                       mfma16x16x32(vf0, aP0, Oacc[dt]));                      \
        }                                                                      \
        __builtin_amdgcn_s_setprio(0);                                         \
    }

    stage(0, 0);

    bf16x8 qf[4];
    {
        const bf16_t* qp = Q + (size_t)(b * S_LEN + q0 + col) * H_DIM +
                           h * HEAD_DIM + quad * 8;
#pragma unroll
        for (int t = 0; t < 4; ++t) qf[t] = *(const bf16x8*)(qp + t * 32);
    }
    f32x4 Oacc[8];
#pragma unroll
    for (int dt = 0; dt < 8; ++dt) Oacc[dt] = (f32x4){0.f, 0.f, 0.f, 0.f};
    float m_i = NEG_BIG, l_i = 0.f;

    int jt = 0;
    while (true) {
        ATTN_STEP(jt, 0)
        if (++jt == nsteps) break;
        ATTN_STEP(jt, 1)
        if (++jt == nsteps) break;
    }

    // normalize and store in place: lane holds O[q=col][d=dt*16+quad*4+r],
    // l_i is indexed by q=col -> direct reciprocal, aligned 8B stores.
    {
        const float inv = 1.0f / l_i;
        const size_t rowoff =
            (size_t)(b * S_LEN + q0 + col) * H_DIM + h * HEAD_DIM + quad * 4;
#pragma unroll
        for (int dt = 0; dt < 8; ++dt) {
            bf16x4 o;
#pragma unroll
            for (int r = 0; r < 4; ++r) o[r] = (bf16_t)(Oacc[dt][r] * inv);
            *(bf16x4*)(Q + rowoff + dt * 16) = o;
        }
    }
#undef ATTN_STEP
}

extern "C" void kernel_launch(void* const* d_in, const int* in_sizes, int n_in,
                              void* d_out, int out_size, void* d_ws, size_t ws_size,
                              hipStream_t stream) {
    const float* X    = (const float*)d_in[0];
    const float* cosb = (const float*)d_in[1];
    const float* sinb = (const float*)d_in[2];
    const float* Wq   = (const float*)d_in[3];
    const float* Wk   = (const float*)d_in[4];
    const float* Wv   = (const float*)d_in[5];
    const float* Wo   = (const float*)d_in[6];
    float* out = (float*)d_out;

    // ws (bf16): Xb 16MB | Wqkv 12MB (q 8, k 2, v 2 contiguous) | Wob 8MB |
    //            Q 16MB | K 4MB | V^T 4MB
    char* ws = (char*)d_ws;
    bf16_t* Xb    = (bf16_t*)(ws);
    bf16_t* Wqkvb = (bf16_t*)(ws + (16u << 20));
    bf16_t* Wkb   = (bf16_t*)(ws + (24u << 20));
    bf16_t* Wvb   = (bf16_t*)(ws + (26u << 20));
    bf16_t* Wob   = (bf16_t*)(ws + (28u << 20));
    bf16_t* qbuf  = (bf16_t*)(ws + (36u << 20));
    bf16_t* kbuf  = (bf16_t*)(ws + (52u << 20));
    bf16_t* vtbuf = (bf16_t*)(ws + (56u << 20));

    dim3 blk(256, 1, 1);
    const int ncvt = N_X + 2 * N_WQ + 2 * N_WK;   // /2048 = 9216 blocks
    cvt_all<<<dim3(ncvt / 2048, 1, 1), blk, 0, stream>>>(
        X, Wq, Wk, Wv, Wo, Xb, Wqkvb, Wkb, Wvb, Wob);

    gemm_qkv<<<dim3(NQKV / 128, NTOK / 128), blk, 0, stream>>>(
        Xb, Wqkvb, cosb, sinb, qbuf, kbuf, vtbuf);
    attn_fwd<<<dim3(512, 1, 1), dim3(512, 1, 1), 0, stream>>>(qbuf, kbuf, vtbuf);
    gemm_out<<<dim3(H_DIM / 128, NTOK / 128), blk, 0, stream>>>(qbuf, Wob, out);

    (void)in_sizes; (void)n_in; (void)out_size; (void)ws_size;
}

// Round 6
// 313.814 us; speedup vs baseline: 1.0023x; 1.0023x over previous
//
#include <hip/hip_runtime.h>
#include <hip/hip_bf16.h>
#include <stdint.h>

#define S_LEN 2048
#define H_DIM 2048
#define NHEADS 16
#define KVHEADS 4
#define HEAD_DIM 128
#define KV_DIM 512       // KVHEADS * HEAD_DIM
#define NTOK 4096        // B * S
#define NQKV 3072        // H_DIM + 2*KV_DIM

typedef __bf16 bf16_t;
typedef __bf16 bf16x8 __attribute__((ext_vector_type(8)));
typedef __bf16 bf16x4 __attribute__((ext_vector_type(4)));
typedef float f32x4 __attribute__((ext_vector_type(4)));

__device__ __forceinline__ f32x4 mfma16x16x32(bf16x8 a, bf16x8 b, f32x4 c) {
    return __builtin_amdgcn_mfma_f32_16x16x32_bf16(a, b, c, 0, 0, 0);
}

// async global->LDS, 16B per lane. LDS dest = wave-uniform base + lane*16;
// global address may be fully per-lane (scatter side is global).
__device__ __forceinline__ void gload_lds16(const bf16_t* g, bf16_t* l) {
    __builtin_amdgcn_global_load_lds(
        (__attribute__((address_space(1))) uint32_t*)(uintptr_t)g,
        (__attribute__((address_space(3))) uint32_t*)l, 16, 0, 0);
}

// Fused fp32->bf16 convert of all 5 tensors + RoPE-table build in one launch.
// Wq/Wk rows are PERMUTED on the fly: phys row j = head*128 + 64s + 16a + c
// takes logical row head*128 + 64(a&1) + 32s + 16(a>>1) + c. This places each
// RoPE pair (d, d+64) into the same epilogue thread of gemm_qkv (ni=2P lo,
// ni=2P+1 hi). Q/K remain dim-permuted in memory; QK^T is invariant since
// the same bijection is applied to both operands, and V/O/gemm_out never see
// the permuted axis.
// The last 64 blocks build rt[tok][dlo] = {cos[dlo], sin[dlo], cos[dlo+64],
// sin[dlo+64]} (float4, 2 MB) so the gemm_qkv epilogue does ONE coalesced
// 16B load per rotation pair instead of 4 scattered scalars (the round-5
// regression). rt lives in the first 2 MB of d_out: written here, read by
// gemm_qkv, wholly overwritten by gemm_out afterwards.
#define N_X  (NTOK * H_DIM)     // 8388608
#define N_WQ (H_DIM * H_DIM)    // 4194304
#define N_WK (KV_DIM * H_DIM)   // 1048576
#define N_TOT (N_X + 2 * N_WQ + 2 * N_WK)   // 18874368
__global__ __launch_bounds__(256) void cvt_all(const float* __restrict__ X,
                                               const float* __restrict__ Wq,
                                               const float* __restrict__ Wk,
                                               const float* __restrict__ Wv,
                                               const float* __restrict__ Wo,
                                               const float* __restrict__ cosb,
                                               const float* __restrict__ sinb,
                                               bf16_t* __restrict__ Xb,
                                               bf16_t* __restrict__ Wqb,
                                               bf16_t* __restrict__ Wkb,
                                               bf16_t* __restrict__ Wvb,
                                               bf16_t* __restrict__ Wob,
                                               float4* __restrict__ rt) {
    long i = (long)(blockIdx.x * 256 + threadIdx.x) * 8;
    if (i >= N_TOT) {
        // RoPE table: 131072 entries, 8 per thread, same token row each.
        const int e   = (int)((i - N_TOT) >> 3);   // 0..16383
        const int tok = e >> 3;
        const int d0  = (e & 7) * 8;
        const float* cb = cosb + tok * HEAD_DIM;
        const float* sb = sinb + tok * HEAD_DIM;
        float4* dst4 = rt + tok * 64 + d0;
#pragma unroll
        for (int u = 0; u < 8; ++u)
            dst4[u] = (float4){cb[d0 + u], sb[d0 + u],
                               cb[d0 + u + 64], sb[d0 + u + 64]};
        return;
    }
    const float* src;
    bf16_t* dst;
    bool perm = false;
    if (i < N_X)                       { src = X;  dst = Xb; }
    else if ((i -= N_X) < N_WQ)        { src = Wq; dst = Wqb; perm = true; }
    else if ((i -= N_WQ) < N_WK)       { src = Wk; dst = Wkb; perm = true; }
    else if ((i -= N_WK) < N_WK)       { src = Wv; dst = Wvb; }
    else      { i -= N_WK;               src = Wo; dst = Wob; }
    long isrc = i;
    if (perm) {
        const long jrow = i >> 11;          // dst row (2048 elems/row)
        const int  o    = (int)(i & 2047);
        const int  a    = (int)(jrow >> 4) & 3;
        const int  sh   = (int)(jrow >> 6) & 1;
        const long srow = (jrow & ~127L) | ((long)(a & 1) << 6) |
                          ((long)sh << 5) | ((long)(a >> 1) << 4) | (jrow & 15);
        isrc = srow * 2048 + o;
    }
    const float4 va = *(const float4*)(src + isrc);
    const float4 vb = *(const float4*)(src + isrc + 4);
    bf16x8 ov;
    ov[0] = (bf16_t)va.x; ov[1] = (bf16_t)va.y; ov[2] = (bf16_t)va.z; ov[3] = (bf16_t)va.w;
    ov[4] = (bf16_t)vb.x; ov[5] = (bf16_t)vb.y; ov[6] = (bf16_t)vb.z; ov[7] = (bf16_t)vb.w;
    *(bf16x8*)(dst + i) = ov;
}

// ---- shared GEMM main loop (m97 structure), used by both GEMM kernels ----
// computes acc[4][4] for this thread's 64x64 wave tile at (m0+wm, n0+wn)
#define GEMM_BODY(A_, W_, K_)                                                  \
    __shared__ alignas(16) bf16_t As[128 * 32];                                \
    __shared__ alignas(16) bf16_t Bs[128 * 32];                                \
    const int tid  = threadIdx.x;                                              \
    const int wave = tid >> 6;                                                 \
    const int lane = tid & 63;                                                 \
    const int col  = lane & 15;                                                \
    const int quad = lane >> 4;                                                \
    const int m0 = blockIdx.y * 128;                                           \
    const int n0 = blockIdx.x * 128;                                           \
    const int wm = (wave >> 1) * 64;                                           \
    const int wn = (wave & 1) * 64;                                            \
    const int r0 = tid >> 2;                                                   \
    const int kk = (tid & 3) * 8;                                              \
    const bf16_t* a0 = (A_) + (size_t)(m0 + r0) * (K_) + kk;                   \
    const bf16_t* a1 = a0 + (size_t)64 * (K_);                                 \
    const bf16_t* b0 = (W_) + (size_t)(n0 + r0) * (K_) + kk;                   \
    const bf16_t* b1 = b0 + (size_t)64 * (K_);                                 \
    bf16_t* lA0 = As + tid * 8;                                                \
    bf16_t* lA1 = As + 2048 + tid * 8;                                         \
    bf16_t* lB0 = Bs + tid * 8;                                                \
    bf16_t* lB1 = Bs + 2048 + tid * 8;                                         \
    f32x4 acc[4][4];                                                           \
    _Pragma("unroll") for (int mi = 0; mi < 4; ++mi)                           \
        _Pragma("unroll") for (int ni = 0; ni < 4; ++ni)                       \
            acc[mi][ni] = (f32x4){0.f, 0.f, 0.f, 0.f};                         \
    for (int k0 = 0; k0 < (K_); k0 += 32) {                                    \
        __syncthreads();                                                       \
        gload_lds16(a0 + k0, lA0);                                             \
        gload_lds16(a1 + k0, lA1);                                             \
        gload_lds16(b0 + k0, lB0);                                             \
        gload_lds16(b1 + k0, lB1);                                             \
        __syncthreads();                                                       \
        bf16x8 av[4], bv[4];                                                   \
        _Pragma("unroll") for (int i = 0; i < 4; ++i) {                        \
            av[i] = *(const bf16x8*)(As + (wm + i * 16 + col) * 32 + quad * 8);\
            bv[i] = *(const bf16x8*)(Bs + (wn + i * 16 + col) * 32 + quad * 8);\
        }                                                                      \
        _Pragma("unroll") for (int mi = 0; mi < 4; ++mi)                       \
            _Pragma("unroll") for (int ni = 0; ni < 4; ++ni)                   \
                acc[mi][ni] = mfma16x16x32(av[mi], bv[ni], acc[mi][ni]);       \
    }

#define QSCALE_LOG2E 0.12753102813264324f  // (1/sqrt(128)) * log2(e)

// Fused QKV projection + RoPE epilogue. C row-major views into qbuf
// [M][2048] (n<2048), kbuf [M][512] (2048<=n<2560), and V^T layout
// [b][kvh*128+d][s] (n>=2560). Wq/Wk were row-permuted in cvt_all so each
// thread's (ni=2P, ni=2P+1) fragments hold a RoPE pair (logical dims dlo,
// dlo+64 with dlo = 32*s_half + 16P + col); the rotation is applied to the
// fp32 accumulator via ONE float4 table load per pair. Q additionally scaled
// by scale*log2e so attn uses exp2 with no per-score multiply.
__global__ __launch_bounds__(256) void gemm_qkv(const bf16_t* __restrict__ A,
                                                const bf16_t* __restrict__ W,
                                                const float4* __restrict__ rt,
                                                bf16_t* __restrict__ qbuf,
                                                bf16_t* __restrict__ kbuf,
                                                bf16_t* __restrict__ vtbuf) {
    GEMM_BODY(A, W, H_DIM)
    const int ng = n0 + wn;   // 64-aligned; q/k/v boundaries are 64-aligned
    if (ng < H_DIM) {
        const int dbase = ((ng >> 6) & 1) * 32 + col;
#pragma unroll
        for (int mi = 0; mi < 4; ++mi) {
#pragma unroll
            for (int r = 0; r < 4; ++r) {
                const int m   = m0 + wm + mi * 16 + quad * 4 + r;
                const int tok = m & (S_LEN - 1);
#pragma unroll
                for (int P = 0; P < 2; ++P) {
                    const float4 t = rt[tok * 64 + dbase + P * 16];
                    const float lo = acc[mi][2 * P][r];
                    const float hi = acc[mi][2 * P + 1][r];
                    qbuf[(size_t)m * H_DIM + ng + (2 * P) * 16 + col] =
                        (bf16_t)((lo * t.x - hi * t.y) * QSCALE_LOG2E);
                    qbuf[(size_t)m * H_DIM + ng + (2 * P + 1) * 16 + col] =
                        (bf16_t)((hi * t.z + lo * t.w) * QSCALE_LOG2E);
                }
            }
        }
    } else if (ng < H_DIM + KV_DIM) {
        const int nrel  = ng - H_DIM;
        const int dbase = ((nrel >> 6) & 1) * 32 + col;
#pragma unroll
        for (int mi = 0; mi < 4; ++mi) {
#pragma unroll
            for (int r = 0; r < 4; ++r) {
                const int m   = m0 + wm + mi * 16 + quad * 4 + r;
                const int tok = m & (S_LEN - 1);
#pragma unroll
                for (int P = 0; P < 2; ++P) {
                    const float4 t = rt[tok * 64 + dbase + P * 16];
                    const float lo = acc[mi][2 * P][r];
                    const float hi = acc[mi][2 * P + 1][r];
                    kbuf[(size_t)m * KV_DIM + nrel + (2 * P) * 16 + col] =
                        (bf16_t)(lo * t.x - hi * t.y);
                    kbuf[(size_t)m * KV_DIM + nrel + (2 * P + 1) * 16 + col] =
                        (bf16_t)(hi * t.z + lo * t.w);
                }
            }
        }
    } else {
#pragma unroll
        for (int mi = 0; mi < 4; ++mi) {
            const int m = m0 + wm + mi * 16 + quad * 4;
#pragma unroll
            for (int ni = 0; ni < 4; ++ni) {
                const int nv = ng - (H_DIM + KV_DIM) + ni * 16 + col;
                const size_t off =
                    ((size_t)(m >> 11) * KV_DIM + nv) * S_LEN + (m & (S_LEN - 1));
                bf16x4 o;
#pragma unroll
                for (int r = 0; r < 4; ++r) o[r] = (bf16_t)acc[mi][ni][r];
                *(bf16x4*)(vtbuf + off) = o;
            }
        }
    }
}

// O projection: fp32 output.
__global__ __launch_bounds__(256) void gemm_out(const bf16_t* __restrict__ A,
                                                const bf16_t* __restrict__ W,
                                                float* __restrict__ C) {
    GEMM_BODY(A, W, H_DIM)
#pragma unroll
    for (int mi = 0; mi < 4; ++mi)
#pragma unroll
        for (int ni = 0; ni < 4; ++ni)
#pragma unroll
            for (int r = 0; r < 4; ++r)
                C[(size_t)(m0 + wm + mi * 16 + quad * 4 + r) * H_DIM +
                  n0 + wn + ni * 16 + col] = (float)acc[mi][ni][r];
}

#define NEG_BIG (-1e30f)
#define TJ 64          // kv tile width
#define DEFER_THR 8.0f // defer-max threshold, log2 units (P bounded by 2^8)

// Flash attention, causal, transposed-score form.
// 8-wave (512-thread) blocks: waves 0-3 own q-tile 2i, waves 4-7 own q-tile
// 2i+1 (one GQA head each); both tiles need the SAME nsteps = i/2+1, so all
// 8 waves run uniform barriers while sharing one K/V staging stream.
// Complementary CU pairing: blocks id and id+256 co-locate on a CU under
// round-robin dispatch; i = (b? 63-j : j) makes each CU's two resident
// blocks' durations sum to exactly 33 steps. LDS = 64 KB -> 2 blocks/CU.
// PV is K=32 MFMA with P^T staged through LDS -- but at ZERO extra LDS: the
// current K tile (16 KB = 8 waves x 2 KB) is dead after QK^T, so after a raw
// s_barrier (NOT __syncthreads: must not drain the in-flight vmcnt prefetch)
// each wave reuses its 2 KB slice of Ks[cur] as wave-private P^T scratch.
// Safety: each wave's K ds_reads complete before its last QK^T MFMA issues
// (compiler waitcnts), so barrier => all K reads done => P writes safe;
// sched_barrier(0) fences code motion around the raw barrier. The DMA always
// targets buffer cur^1, P always buffer cur -> no overlap.
// PV operand order mfma(vf, aP): D = O^T, layout O[q=col][d=dt*16+quad*4+r]
// -> alpha/l rescale is broadcast-free (indexed by q=col) and the epilogue
// stores are aligned bf16x4.
// NOTE: Q and K arrive dim-PERMUTED (see cvt_all); QK^T is invariant because
// both operands carry the same bijection on the contraction axis.
__global__ __launch_bounds__(512, 4) void attn_fwd(bf16_t* __restrict__ Q,
                                                   const bf16_t* __restrict__ Kb,
                                                   const bf16_t* __restrict__ Vt) {
    const int id   = blockIdx.x;       // 0..511
    const int jp   = id & 63;
    const int kvh  = (id >> 6) & 3;
    const int b    = id >> 8;
    const int i    = b ? (63 - jp) : jp;   // complementary pairing per CU
    const int tid  = threadIdx.x;
    const int wave = tid >> 6;
    const int lane = tid & 63;
    const int col  = lane & 15;
    const int quad = lane >> 4;
    const int grp  = wave >> 2;        // 0: tile 2i, 1: tile 2i+1
    const int h    = kvh * 4 + (wave & 3);
    const int q0   = (2 * i + grp) * 16;
    const int nsteps = (i >> 1) + 1;
    const int swz  = col & 7;          // read-side swizzle key

    // chunk-swizzled tiles: slot(j,c) = j*16 + (c^(j&7)) for K [64j][16c],
    // slot(d,cj) = d*8 + (cj^(d&7)) for V^T [128d][8cj]; elem addr = slot*8.
    __shared__ alignas(16) bf16_t Ks[2][TJ * HEAD_DIM];    // 16 KB each
    __shared__ alignas(16) bf16_t Vs[2][HEAD_DIM * TJ];    // 16 KB each

    const bf16_t* kbase = Kb + (size_t)(b * S_LEN) * KV_DIM + kvh * HEAD_DIM;
    const bf16_t* vtb   = Vt + (size_t)(b * KVHEADS + kvh) * HEAD_DIM * S_LEN;

    // per-lane global element offsets for the 2 K + 2 V staging DMAs
    int kgoff[2], vgoff[2];
#pragma unroll
    for (int im = 0; im < 2; ++im) {
        const int s = im * 512 + tid;
        const int jr = s >> 4, c = (s & 15) ^ (jr & 7);
        kgoff[im] = jr * KV_DIM + c * 8;
        const int d = s >> 3, cj = (s & 7) ^ (d & 7);
        vgoff[im] = d * S_LEN + cj * 8;
    }
    auto stage = [&](int buf, int j0) {
        const bf16_t* kb = kbase + (size_t)j0 * KV_DIM;
        const bf16_t* vb = vtb + j0;
#pragma unroll
        for (int im = 0; im < 2; ++im) {
            gload_lds16(kb + kgoff[im], &Ks[buf][(im * 512 + wave * 64) * 8]);
            gload_lds16(vb + vgoff[im], &Vs[buf][(im * 512 + wave * 64) * 8]);
        }
    };

    // hoisted fragment LDS byte addrs; tile index goes into imm offsets:
    // K frag (t,jc): kaddr[t] + jc*4096;  V frag (half,dt): vb0/1 + dt*2048
    int kaddr[4];
#pragma unroll
    for (int t = 0; t < 4; ++t)
        kaddr[t] = col * 256 + (((4 * t + quad) ^ swz) << 4);
    const int vb0 = col * 128 + ((quad ^ swz) << 4);
    const int vb1 = col * 128 + (((quad + 4) ^ swz) << 4);
    // P^T scratch offsets within the dead K tile (wave-private 2 KB slice):
    // logical [q=col][j] row-major 128 B/row, XOR-swizzled by (col&7)<<4.
    int pwoff[4];
#pragma unroll
    for (int jc = 0; jc < 4; ++jc)
        pwoff[jc] = wave * 2048 +
                    ((col * 128 + jc * 32 + quad * 8) ^ (swz << 4));
    const int ap0 = wave * 2048 + ((col * 128 + quad * 16) ^ (swz << 4));
    const int ap1 = wave * 2048 + ((col * 128 + 64 + quad * 16) ^ (swz << 4));

// one kv-step with compile-time buffer index BUF (so the +16KiB buffer
// stride folds into ds_read offset immediates -> zero address VALU in loop)
#define ATTN_STEP(JT, BUF)                                                     \
    {                                                                          \
        const int jt_ = (JT);                                                  \
        const bool last_ = (jt_ == nsteps - 1);                                \
        __syncthreads();  /* vmcnt(0) drain: buf BUF staged; prev reads done */\
        if (!last_) stage((BUF) ^ 1, (jt_ + 1) * TJ);                          \
        const char* ksb = (const char*)Ks[(BUF)];                              \
        const char* vsb = (const char*)Vs[(BUF)];                              \
        char* pwb = (char*)Ks[(BUF)];   /* dead after QK^T; P^T scratch */     \
        f32x4 sc[4];                                                           \
        _Pragma("unroll") for (int jc = 0; jc < 4; ++jc)                       \
            sc[jc] = (f32x4){0.f, 0.f, 0.f, 0.f};                              \
        __builtin_amdgcn_s_setprio(1);                                         \
        _Pragma("unroll") for (int t = 0; t < 4; ++t)                          \
            _Pragma("unroll") for (int jc = 0; jc < 4; ++jc)                   \
                sc[jc] = mfma16x16x32(                                         \
                    *(const bf16x8*)(ksb + kaddr[t] + jc * 4096), qf[t],       \
                    sc[jc]);                                                   \
        __builtin_amdgcn_s_setprio(0);                                         \
        if (last_) {                                                           \
            const int j0_ = jt_ * TJ;                                          \
            const int q_ = q0 + col;                                           \
            _Pragma("unroll") for (int jc = 0; jc < 4; ++jc)                   \
                _Pragma("unroll") for (int r = 0; r < 4; ++r) {                \
                    const int j = j0_ + jc * 16 + quad * 4 + r;                \
                    if (j > q_) sc[jc][r] = NEG_BIG;                           \
                }                                                              \
        }                                                                      \
        float mx = sc[0][0];                                                   \
        _Pragma("unroll") for (int jc = 0; jc < 4; ++jc)                       \
            _Pragma("unroll") for (int r = 0; r < 4; ++r)                      \
                mx = fmaxf(mx, sc[jc][r]);                                     \
        /* per-lane partial max is a lower bound of the column max: if no  */  \
        /* lane exceeds m_i+THR, no column max does -> skip reduce+rescale */  \
        if (!__all(mx <= m_i + DEFER_THR)) {                                   \
            mx = fmaxf(mx, __shfl_xor(mx, 16));                                \
            mx = fmaxf(mx, __shfl_xor(mx, 32));                                \
            const float mn = fmaxf(m_i, mx);                                   \
            const float alpha = __builtin_amdgcn_exp2f(m_i - mn);              \
            m_i = mn;                                                          \
            l_i *= alpha;                                                      \
            _Pragma("unroll") for (int dt = 0; dt < 8; ++dt)                   \
                Oacc[dt] *= alpha;  /* O rows are q=col: no broadcast */       \
        }                                                                      \
        float sum = 0.f;                                                       \
        bf16x4 pb[4];                                                          \
        _Pragma("unroll") for (int jc = 0; jc < 4; ++jc)                       \
            _Pragma("unroll") for (int r = 0; r < 4; ++r) {                    \
                const float pe = __builtin_amdgcn_exp2f(sc[jc][r] - m_i);      \
                sum += pe;                                                     \
                pb[jc][r] = (bf16_t)pe;                                        \
            }                                                                  \
        /* barrier: every wave's K-reads are complete; K tile becomes P^T */   \
        __builtin_amdgcn_sched_barrier(0);                                     \
        __builtin_amdgcn_s_barrier();                                          \
        __builtin_amdgcn_sched_barrier(0);                                     \
        _Pragma("unroll") for (int jc = 0; jc < 4; ++jc)                       \
            *(bf16x4*)(pwb + pwoff[jc]) = pb[jc];                              \
        sum += __shfl_xor(sum, 16);                                            \
        sum += __shfl_xor(sum, 32);                                            \
        l_i += sum;                                                            \
        asm volatile("s_waitcnt lgkmcnt(0)" ::: "memory");  /* P visible */    \
        const bf16x8 aP0 = *(const bf16x8*)(pwb + ap0);                        \
        const bf16x8 aP1 = *(const bf16x8*)(pwb + ap1);                        \
        __builtin_amdgcn_s_setprio(1);                                         \
        _Pragma("unroll") for (int dt = 0; dt < 8; ++dt) {                     \
            const bf16x8 vf0 = *(const bf16x8*)(vsb + vb0 + dt * 2048);        \
            const bf16x8 vf1 = *(const bf16x8*)(vsb + vb1 + dt * 2048);        \
            Oacc[dt] = mfma16x16x32(vf1, aP1,                                  \
                       mfma16x16x32(vf0, aP0, Oacc[dt]));                      \
        }                                                                      \
        __builtin_amdgcn_s_setprio(0);                                         \
    }

    stage(0, 0);

    bf16x8 qf[4];
    {
        const bf16_t* qp = Q + (size_t)(b * S_LEN + q0 + col) * H_DIM +
                           h * HEAD_DIM + quad * 8;
#pragma unroll
        for (int t = 0; t < 4; ++t) qf[t] = *(const bf16x8*)(qp + t * 32);
    }
    f32x4 Oacc[8];
#pragma unroll
    for (int dt = 0; dt < 8; ++dt) Oacc[dt] = (f32x4){0.f, 0.f, 0.f, 0.f};
    float m_i = NEG_BIG, l_i = 0.f;

    int jt = 0;
    while (true) {
        ATTN_STEP(jt, 0)
        if (++jt == nsteps) break;
        ATTN_STEP(jt, 1)
        if (++jt == nsteps) break;
    }

    // normalize and store in place: lane holds O[q=col][d=dt*16+quad*4+r],
    // l_i is indexed by q=col -> direct reciprocal, aligned 8B stores.
    {
        const float inv = 1.0f / l_i;
        const size_t rowoff =
            (size_t)(b * S_LEN + q0 + col) * H_DIM + h * HEAD_DIM + quad * 4;
#pragma unroll
        for (int dt = 0; dt < 8; ++dt) {
            bf16x4 o;
#pragma unroll
            for (int r = 0; r < 4; ++r) o[r] = (bf16_t)(Oacc[dt][r] * inv);
            *(bf16x4*)(Q + rowoff + dt * 16) = o;
        }
    }
#undef ATTN_STEP
}

extern "C" void kernel_launch(void* const* d_in, const int* in_sizes, int n_in,
                              void* d_out, int out_size, void* d_ws, size_t ws_size,
                              hipStream_t stream) {
    const float* X    = (const float*)d_in[0];
    const float* cosb = (const float*)d_in[1];
    const float* sinb = (const float*)d_in[2];
    const float* Wq   = (const float*)d_in[3];
    const float* Wk   = (const float*)d_in[4];
    const float* Wv   = (const float*)d_in[5];
    const float* Wo   = (const float*)d_in[6];
    float* out = (float*)d_out;

    // ws (bf16): Xb 16MB | Wqkv 12MB (q 8, k 2, v 2 contiguous) | Wob 8MB |
    //            Q 16MB | K 4MB | V^T 4MB
    // RoPE table rt (2MB, float4) lives in d_out's first 2MB: written by
    // cvt_all, read by gemm_qkv, wholly overwritten by gemm_out at the end.
    char* ws = (char*)d_ws;
    bf16_t* Xb    = (bf16_t*)(ws);
    bf16_t* Wqkvb = (bf16_t*)(ws + (16u << 20));
    bf16_t* Wkb   = (bf16_t*)(ws + (24u << 20));
    bf16_t* Wvb   = (bf16_t*)(ws + (26u << 20));
    bf16_t* Wob   = (bf16_t*)(ws + (28u << 20));
    bf16_t* qbuf  = (bf16_t*)(ws + (36u << 20));
    bf16_t* kbuf  = (bf16_t*)(ws + (52u << 20));
    bf16_t* vtbuf = (bf16_t*)(ws + (56u << 20));
    float4* rt    = (float4*)d_out;

    dim3 blk(256, 1, 1);
    const int ncvt = N_TOT / 2048 + 64;   // 9216 convert + 64 table blocks
    cvt_all<<<dim3(ncvt, 1, 1), blk, 0, stream>>>(
        X, Wq, Wk, Wv, Wo, cosb, sinb, Xb, Wqkvb, Wkb, Wvb, Wob, rt);

    gemm_qkv<<<dim3(NQKV / 128, NTOK / 128), blk, 0, stream>>>(
        Xb, Wqkvb, (const float4*)rt, qbuf, kbuf, vtbuf);
    attn_fwd<<<dim3(512, 1, 1), dim3(512, 1, 1), 0, stream>>>(qbuf, kbuf, vtbuf);
    gemm_out<<<dim3(H_DIM / 128, NTOK / 128), blk, 0, stream>>>(qbuf, Wob, out);

    (void)in_sizes; (void)n_in; (void)out_size; (void)ws_size;
}

// Round 7
// 290.812 us; speedup vs baseline: 1.0815x; 1.0791x over previous
//
#include <hip/hip_runtime.h>
#include <hip/hip_bf16.h>
#include <stdint.h>

#define S_LEN 2048
#define H_DIM 2048
#define NHEADS 16
#define KVHEADS 4
#define HEAD_DIM 128
#define KV_DIM 512       // KVHEADS * HEAD_DIM
#define NTOK 4096        // B * S
#define NQKV 3072        // H_DIM + 2*KV_DIM

typedef __bf16 bf16_t;
typedef __bf16 bf16x8 __attribute__((ext_vector_type(8)));
typedef __bf16 bf16x4 __attribute__((ext_vector_type(4)));
typedef float f32x4 __attribute__((ext_vector_type(4)));

__device__ __forceinline__ f32x4 mfma16x16x32(bf16x8 a, bf16x8 b, f32x4 c) {
    return __builtin_amdgcn_mfma_f32_16x16x32_bf16(a, b, c, 0, 0, 0);
}

// async global->LDS, 16B per lane. LDS dest = wave-uniform base + lane*16;
// global address may be fully per-lane (scatter side is global).
__device__ __forceinline__ void gload_lds16(const bf16_t* g, bf16_t* l) {
    __builtin_amdgcn_global_load_lds(
        (__attribute__((address_space(1))) uint32_t*)(uintptr_t)g,
        (__attribute__((address_space(3))) uint32_t*)l, 16, 0, 0);
}

// Fused fp32->bf16 convert of all 5 tensors in one launch (8 elems/thread).
#define N_X  (NTOK * H_DIM)     // 8388608
#define N_WQ (H_DIM * H_DIM)    // 4194304
#define N_WK (KV_DIM * H_DIM)   // 1048576
__global__ __launch_bounds__(256) void cvt_all(const float* __restrict__ X,
                                               const float* __restrict__ Wq,
                                               const float* __restrict__ Wk,
                                               const float* __restrict__ Wv,
                                               const float* __restrict__ Wo,
                                               bf16_t* __restrict__ Xb,
                                               bf16_t* __restrict__ Wqb,
                                               bf16_t* __restrict__ Wkb,
                                               bf16_t* __restrict__ Wvb,
                                               bf16_t* __restrict__ Wob) {
    long i = (long)(blockIdx.x * 256 + threadIdx.x) * 8;
    const float* src;
    bf16_t* dst;
    if (i < N_X)                       { src = X;  dst = Xb; }
    else if ((i -= N_X) < N_WQ)        { src = Wq; dst = Wqb; }
    else if ((i -= N_WQ) < N_WK)       { src = Wk; dst = Wkb; }
    else if ((i -= N_WK) < N_WK)       { src = Wv; dst = Wvb; }
    else      { i -= N_WK;               src = Wo; dst = Wob; }
    const float4 a = *(const float4*)(src + i);
    const float4 b = *(const float4*)(src + i + 4);
    bf16x8 o;
    o[0] = (bf16_t)a.x; o[1] = (bf16_t)a.y; o[2] = (bf16_t)a.z; o[3] = (bf16_t)a.w;
    o[4] = (bf16_t)b.x; o[5] = (bf16_t)b.y; o[6] = (bf16_t)b.z; o[7] = (bf16_t)b.w;
    *(bf16x8*)(dst + i) = o;
}

// ---- shared GEMM main loop (m97 structure), used by both GEMM kernels ----
// computes acc[4][4] for this thread's 64x64 wave tile at (m0+wm, n0+wn)
#define GEMM_BODY(A_, W_, K_)                                                  \
    __shared__ alignas(16) bf16_t As[128 * 32];                                \
    __shared__ alignas(16) bf16_t Bs[128 * 32];                                \
    const int tid  = threadIdx.x;                                              \
    const int wave = tid >> 6;                                                 \
    const int lane = tid & 63;                                                 \
    const int col  = lane & 15;                                                \
    const int quad = lane >> 4;                                                \
    const int m0 = blockIdx.y * 128;                                           \
    const int n0 = blockIdx.x * 128;                                           \
    const int wm = (wave >> 1) * 64;                                           \
    const int wn = (wave & 1) * 64;                                            \
    const int r0 = tid >> 2;                                                   \
    const int kk = (tid & 3) * 8;                                              \
    const bf16_t* a0 = (A_) + (size_t)(m0 + r0) * (K_) + kk;                   \
    const bf16_t* a1 = a0 + (size_t)64 * (K_);                                 \
    const bf16_t* b0 = (W_) + (size_t)(n0 + r0) * (K_) + kk;                   \
    const bf16_t* b1 = b0 + (size_t)64 * (K_);                                 \
    bf16_t* lA0 = As + tid * 8;                                                \
    bf16_t* lA1 = As + 2048 + tid * 8;                                         \
    bf16_t* lB0 = Bs + tid * 8;                                                \
    bf16_t* lB1 = Bs + 2048 + tid * 8;                                         \
    f32x4 acc[4][4];                                                           \
    _Pragma("unroll") for (int mi = 0; mi < 4; ++mi)                           \
        _Pragma("unroll") for (int ni = 0; ni < 4; ++ni)                       \
            acc[mi][ni] = (f32x4){0.f, 0.f, 0.f, 0.f};                         \
    for (int k0 = 0; k0 < (K_); k0 += 32) {                                    \
        __syncthreads();                                                       \
        gload_lds16(a0 + k0, lA0);                                             \
        gload_lds16(a1 + k0, lA1);                                             \
        gload_lds16(b0 + k0, lB0);                                             \
        gload_lds16(b1 + k0, lB1);                                             \
        __syncthreads();                                                       \
        bf16x8 av[4], bv[4];                                                   \
        _Pragma("unroll") for (int i = 0; i < 4; ++i) {                        \
            av[i] = *(const bf16x8*)(As + (wm + i * 16 + col) * 32 + quad * 8);\
            bv[i] = *(const bf16x8*)(Bs + (wn + i * 16 + col) * 32 + quad * 8);\
        }                                                                      \
        _Pragma("unroll") for (int mi = 0; mi < 4; ++mi)                       \
            _Pragma("unroll") for (int ni = 0; ni < 4; ++ni)                   \
                acc[mi][ni] = mfma16x16x32(av[mi], bv[ni], acc[mi][ni]);       \
    }

// Fused QKV projection: C row-major views into qbuf [M][2048] (n<2048),
// kbuf [M][512] (2048<=n<2560), and V^T layout [b][kvh*128+d][s] (n>=2560).
__global__ __launch_bounds__(256) void gemm_qkv(const bf16_t* __restrict__ A,
                                                const bf16_t* __restrict__ W,
                                                bf16_t* __restrict__ qbuf,
                                                bf16_t* __restrict__ kbuf,
                                                bf16_t* __restrict__ vtbuf) {
    GEMM_BODY(A, W, H_DIM)
    const int ng = n0 + wn;   // 64-aligned; q/k/v boundaries are 64-aligned
    if (ng < H_DIM) {
#pragma unroll
        for (int mi = 0; mi < 4; ++mi)
#pragma unroll
            for (int ni = 0; ni < 4; ++ni)
#pragma unroll
                for (int r = 0; r < 4; ++r)
                    qbuf[(size_t)(m0 + wm + mi * 16 + quad * 4 + r) * H_DIM +
                         ng + ni * 16 + col] = (bf16_t)acc[mi][ni][r];
    } else if (ng < H_DIM + KV_DIM) {
#pragma unroll
        for (int mi = 0; mi < 4; ++mi)
#pragma unroll
            for (int ni = 0; ni < 4; ++ni)
#pragma unroll
                for (int r = 0; r < 4; ++r)
                    kbuf[(size_t)(m0 + wm + mi * 16 + quad * 4 + r) * KV_DIM +
                         ng - H_DIM + ni * 16 + col] = (bf16_t)acc[mi][ni][r];
    } else {
#pragma unroll
        for (int mi = 0; mi < 4; ++mi) {
            const int m = m0 + wm + mi * 16 + quad * 4;
#pragma unroll
            for (int ni = 0; ni < 4; ++ni) {
                const int nv = ng - (H_DIM + KV_DIM) + ni * 16 + col;
                const size_t off =
                    ((size_t)(m >> 11) * KV_DIM + nv) * S_LEN + (m & (S_LEN - 1));
                bf16x4 o;
#pragma unroll
                for (int r = 0; r < 4; ++r) o[r] = (bf16_t)acc[mi][ni][r];
                *(bf16x4*)(vtbuf + off) = o;
            }
        }
    }
}

// O projection: fp32 output.
__global__ __launch_bounds__(256) void gemm_out(const bf16_t* __restrict__ A,
                                                const bf16_t* __restrict__ W,
                                                float* __restrict__ C) {
    GEMM_BODY(A, W, H_DIM)
#pragma unroll
    for (int mi = 0; mi < 4; ++mi)
#pragma unroll
        for (int ni = 0; ni < 4; ++ni)
#pragma unroll
            for (int r = 0; r < 4; ++r)
                C[(size_t)(m0 + wm + mi * 16 + quad * 4 + r) * H_DIM +
                  n0 + wn + ni * 16 + col] = (float)acc[mi][ni][r];
}

// In-place RoPE on Q [NTOK][2048] (16 heads) and K [NTOK][512] (4 heads).
// Vectorized: 8 rotation pairs per thread (bf16x8 loads/stores, float4
// cos/sin). Q additionally pre-multiplied by scale*log2(e) so attn can use
// exp2 directly with no per-score multiply (attn overwrites Q with O before
// gemm_out reads it, so the scaling never leaks downstream).
#define QSCALE_LOG2E 0.12753102813264324f  // (1/sqrt(128)) * log2(e)
__global__ __launch_bounds__(256) void rope_inplace(bf16_t* __restrict__ Qb,
                                                    bf16_t* __restrict__ Kb,
                                                    const float* __restrict__ cosb,
                                                    const float* __restrict__ sinb) {
    const int idx  = blockIdx.x * 256 + threadIdx.x;  // NTOK*20*8 threads
    const int d8   = (idx & 7) * 8;
    const int rem  = idx >> 3;
    const int head = rem % 20;
    const int row  = rem / 20;
    const int s = row & (S_LEN - 1);
    const float4* cb = (const float4*)(cosb + s * HEAD_DIM);
    const float4* sb = (const float4*)(sinb + s * HEAD_DIM);
    float c0[8], s0[8], c1[8], s1[8];
    *(float4*)&c0[0] = cb[d8 >> 2];        *(float4*)&c0[4] = cb[(d8 >> 2) + 1];
    *(float4*)&s0[0] = sb[d8 >> 2];        *(float4*)&s0[4] = sb[(d8 >> 2) + 1];
    *(float4*)&c1[0] = cb[16 + (d8 >> 2)]; *(float4*)&c1[4] = cb[17 + (d8 >> 2)];
    *(float4*)&s1[0] = sb[16 + (d8 >> 2)]; *(float4*)&s1[4] = sb[17 + (d8 >> 2)];
    bf16_t* base = (head < NHEADS)
        ? Qb + (size_t)row * H_DIM + head * HEAD_DIM
        : Kb + (size_t)row * KV_DIM + (head - NHEADS) * HEAD_DIM;
    const float qs = (head < NHEADS) ? QSCALE_LOG2E : 1.0f;
    const bf16x8 lo = *(const bf16x8*)(base + d8);
    const bf16x8 hi = *(const bf16x8*)(base + d8 + 64);
    bf16x8 olo, ohi;
#pragma unroll
    for (int u = 0; u < 8; ++u) {
        const float lf = (float)lo[u];
        const float hf = (float)hi[u];
        olo[u] = (bf16_t)((lf * c0[u] - hf * s0[u]) * qs);
        ohi[u] = (bf16_t)((hf * c1[u] + lf * s1[u]) * qs);
    }
    *(bf16x8*)(base + d8)      = olo;
    *(bf16x8*)(base + d8 + 64) = ohi;
}

#define NEG_BIG (-1e30f)
#define TJ 64          // kv tile width
#define DEFER_THR 8.0f // defer-max threshold, log2 units (P bounded by 2^8)

// Flash attention, causal, transposed-score form.
// 8-wave (512-thread) blocks: waves 0-3 own q-tile 2i, waves 4-7 own q-tile
// 2i+1 (one GQA head each); both tiles need the SAME nsteps = i/2+1, so all
// 8 waves run uniform barriers while sharing one K/V staging stream.
// Complementary CU pairing: blocks id and id+256 co-locate on a CU under
// round-robin dispatch; i = (b? 63-j : j) makes each CU's two resident
// blocks' durations sum to exactly 33 steps.
// PV is K=32 MFMA with P^T staged through a DEDICATED wave-private LDS
// scratch Ps (8 x 2 KB). LDS total = 80 KB -> still exactly 2 blocks/CU,
// and unlike the round-4 K-tile-reuse trick this needs NO mid-step block
// barrier (Ps never aliases K/V): one __syncthreads per kv-step total, so
// waves slip independently through softmax+PV and overlap on the SIMDs.
// DS ops complete in order per wave, so the lgkmcnt(0) before the P reads
// orders the preceding P writes; the Ks/Vs DMA-vs-read hazard is unchanged
// (top-of-step __syncthreads, DMA always targets buffer BUF^1).
// PV operand order mfma(vf, aP): D = O^T, layout O[q=col][d=dt*16+quad*4+r]
// -> alpha/l rescale is broadcast-free (indexed by q=col) and the epilogue
// stores are aligned bf16x4.
__global__ __launch_bounds__(512, 4) void attn_fwd(bf16_t* __restrict__ Q,
                                                   const bf16_t* __restrict__ Kb,
                                                   const bf16_t* __restrict__ Vt) {
    const int id   = blockIdx.x;       // 0..511
    const int jp   = id & 63;
    const int kvh  = (id >> 6) & 3;
    const int b    = id >> 8;
    const int i    = b ? (63 - jp) : jp;   // complementary pairing per CU
    const int tid  = threadIdx.x;
    const int wave = tid >> 6;
    const int lane = tid & 63;
    const int col  = lane & 15;
    const int quad = lane >> 4;
    const int grp  = wave >> 2;        // 0: tile 2i, 1: tile 2i+1
    const int h    = kvh * 4 + (wave & 3);
    const int q0   = (2 * i + grp) * 16;
    const int nsteps = (i >> 1) + 1;
    const int swz  = col & 7;          // read-side swizzle key

    // chunk-swizzled tiles: slot(j,c) = j*16 + (c^(j&7)) for K [64j][16c],
    // slot(d,cj) = d*8 + (cj^(d&7)) for V^T [128d][8cj]; elem addr = slot*8.
    __shared__ alignas(16) bf16_t Ks[2][TJ * HEAD_DIM];    // 16 KB each
    __shared__ alignas(16) bf16_t Vs[2][HEAD_DIM * TJ];    // 16 KB each
    __shared__ alignas(16) bf16_t Ps[8 * 1024];            // 16 KB, wave-priv

    const bf16_t* kbase = Kb + (size_t)(b * S_LEN) * KV_DIM + kvh * HEAD_DIM;
    const bf16_t* vtb   = Vt + (size_t)(b * KVHEADS + kvh) * HEAD_DIM * S_LEN;

    // per-lane global element offsets for the 2 K + 2 V staging DMAs
    int kgoff[2], vgoff[2];
#pragma unroll
    for (int im = 0; im < 2; ++im) {
        const int s = im * 512 + tid;
        const int jr = s >> 4, c = (s & 15) ^ (jr & 7);
        kgoff[im] = jr * KV_DIM + c * 8;
        const int d = s >> 3, cj = (s & 7) ^ (d & 7);
        vgoff[im] = d * S_LEN + cj * 8;
    }
    auto stage = [&](int buf, int j0) {
        const bf16_t* kb = kbase + (size_t)j0 * KV_DIM;
        const bf16_t* vb = vtb + j0;
#pragma unroll
        for (int im = 0; im < 2; ++im) {
            gload_lds16(kb + kgoff[im], &Ks[buf][(im * 512 + wave * 64) * 8]);
            gload_lds16(vb + vgoff[im], &Vs[buf][(im * 512 + wave * 64) * 8]);
        }
    };

    // hoisted fragment LDS byte addrs; tile index goes into imm offsets:
    // K frag (t,jc): kaddr[t] + jc*4096;  V frag (half,dt): vb0/1 + dt*2048
    int kaddr[4];
#pragma unroll
    for (int t = 0; t < 4; ++t)
        kaddr[t] = col * 256 + (((4 * t + quad) ^ swz) << 4);
    const int vb0 = col * 128 + ((quad ^ swz) << 4);
    const int vb1 = col * 128 + (((quad + 4) ^ swz) << 4);
    // P^T scratch offsets (wave-private 2 KB slice of Ps):
    // logical [q=col][j] row-major 128 B/row, XOR-swizzled by (col&7)<<4.
    int pwoff[4];
#pragma unroll
    for (int jc = 0; jc < 4; ++jc)
        pwoff[jc] = wave * 2048 +
                    ((col * 128 + jc * 32 + quad * 8) ^ (swz << 4));
    const int ap0 = wave * 2048 + ((col * 128 + quad * 16) ^ (swz << 4));
    const int ap1 = wave * 2048 + ((col * 128 + 64 + quad * 16) ^ (swz << 4));

// one kv-step with compile-time buffer index BUF (so the +16KiB buffer
// stride folds into ds_read offset immediates -> zero address VALU in loop)
#define ATTN_STEP(JT, BUF)                                                     \
    {                                                                          \
        const int jt_ = (JT);                                                  \
        const bool last_ = (jt_ == nsteps - 1);                                \
        __syncthreads();  /* vmcnt(0) drain: buf BUF staged; prev reads done */\
        if (!last_) stage((BUF) ^ 1, (jt_ + 1) * TJ);                          \
        const char* ksb = (const char*)Ks[(BUF)];                              \
        const char* vsb = (const char*)Vs[(BUF)];                              \
        char* pwb = (char*)Ps;          /* wave-private P^T scratch */         \
        f32x4 sc[4];                                                           \
        _Pragma("unroll") for (int jc = 0; jc < 4; ++jc)                       \
            sc[jc] = (f32x4){0.f, 0.f, 0.f, 0.f};                              \
        __builtin_amdgcn_s_setprio(1);                                         \
        _Pragma("unroll") for (int t = 0; t < 4; ++t)                          \
            _Pragma("unroll") for (int jc = 0; jc < 4; ++jc)                   \
                sc[jc] = mfma16x16x32(                                         \
                    *(const bf16x8*)(ksb + kaddr[t] + jc * 4096), qf[t],       \
                    sc[jc]);                                                   \
        __builtin_amdgcn_s_setprio(0);                                         \
        if (last_) {                                                           \
            const int j0_ = jt_ * TJ;                                          \
            const int q_ = q0 + col;                                           \
            _Pragma("unroll") for (int jc = 0; jc < 4; ++jc)                   \
                _Pragma("unroll") for (int r = 0; r < 4; ++r) {                \
                    const int j = j0_ + jc * 16 + quad * 4 + r;                \
                    if (j > q_) sc[jc][r] = NEG_BIG;                           \
                }                                                              \
        }                                                                      \
        float mx = sc[0][0];                                                   \
        _Pragma("unroll") for (int jc = 0; jc < 4; ++jc)                       \
            _Pragma("unroll") for (int r = 0; r < 4; ++r)                      \
                mx = fmaxf(mx, sc[jc][r]);                                     \
        /* per-lane partial max is a lower bound of the column max: if no  */  \
        /* lane exceeds m_i+THR, no column max does -> skip reduce+rescale */  \
        if (!__all(mx <= m_i + DEFER_THR)) {                                   \
            mx = fmaxf(mx, __shfl_xor(mx, 16));                                \
            mx = fmaxf(mx, __shfl_xor(mx, 32));                                \
            const float mn = fmaxf(m_i, mx);                                   \
            const float alpha = __builtin_amdgcn_exp2f(m_i - mn);              \
            m_i = mn;                                                          \
            l_i *= alpha;                                                      \
            _Pragma("unroll") for (int dt = 0; dt < 8; ++dt)                   \
                Oacc[dt] *= alpha;  /* O rows are q=col: no broadcast */       \
        }                                                                      \
        float sum = 0.f;                                                       \
        bf16x4 pb[4];                                                          \
        _Pragma("unroll") for (int jc = 0; jc < 4; ++jc)                       \
            _Pragma("unroll") for (int r = 0; r < 4; ++r) {                    \
                const float pe = __builtin_amdgcn_exp2f(sc[jc][r] - m_i);      \
                sum += pe;                                                     \
                pb[jc][r] = (bf16_t)pe;                                        \
            }                                                                  \
        _Pragma("unroll") for (int jc = 0; jc < 4; ++jc)                       \
            *(bf16x4*)(pwb + pwoff[jc]) = pb[jc];                              \
        sum += __shfl_xor(sum, 16);                                            \
        sum += __shfl_xor(sum, 32);                                            \
        l_i += sum;                                                            \
        asm volatile("s_waitcnt lgkmcnt(0)" ::: "memory");  /* P visible */    \
        const bf16x8 aP0 = *(const bf16x8*)(pwb + ap0);                        \
        const bf16x8 aP1 = *(const bf16x8*)(pwb + ap1);                        \
        __builtin_amdgcn_s_setprio(1);                                         \
        _Pragma("unroll") for (int dt = 0; dt < 8; ++dt) {                     \
            const bf16x8 vf0 = *(const bf16x8*)(vsb + vb0 + dt * 2048);        \
            const bf16x8 vf1 = *(const bf16x8*)(vsb + vb1 + dt * 2048);        \
            Oacc[dt] = mfma16x16x32(vf1, aP1,                                  \
                       mfma16x16x32(vf0, aP0, Oacc[dt]));                      \
        }                                                                      \
        __builtin_amdgcn_s_setprio(0);                                         \
    }

    stage(0, 0);

    bf16x8 qf[4];
    {
        const bf16_t* qp = Q + (size_t)(b * S_LEN + q0 + col) * H_DIM +
                           h * HEAD_DIM + quad * 8;
#pragma unroll
        for (int t = 0; t < 4; ++t) qf[t] = *(const bf16x8*)(qp + t * 32);
    }
    f32x4 Oacc[8];
#pragma unroll
    for (int dt = 0; dt < 8; ++dt) Oacc[dt] = (f32x4){0.f, 0.f, 0.f, 0.f};
    float m_i = NEG_BIG, l_i = 0.f;

    int jt = 0;
    while (true) {
        ATTN_STEP(jt, 0)
        if (++jt == nsteps) break;
        ATTN_STEP(jt, 1)
        if (++jt == nsteps) break;
    }

    // normalize and store in place: lane holds O[q=col][d=dt*16+quad*4+r],
    // l_i is indexed by q=col -> direct reciprocal, aligned 8B stores.
    {
        const float inv = 1.0f / l_i;
        const size_t rowoff =
            (size_t)(b * S_LEN + q0 + col) * H_DIM + h * HEAD_DIM + quad * 4;
#pragma unroll
        for (int dt = 0; dt < 8; ++dt) {
            bf16x4 o;
#pragma unroll
            for (int r = 0; r < 4; ++r) o[r] = (bf16_t)(Oacc[dt][r] * inv);
            *(bf16x4*)(Q + rowoff + dt * 16) = o;
        }
    }
#undef ATTN_STEP
}

extern "C" void kernel_launch(void* const* d_in, const int* in_sizes, int n_in,
                              void* d_out, int out_size, void* d_ws, size_t ws_size,
                              hipStream_t stream) {
    const float* X    = (const float*)d_in[0];
    const float* cosb = (const float*)d_in[1];
    const float* sinb = (const float*)d_in[2];
    const float* Wq   = (const float*)d_in[3];
    const float* Wk   = (const float*)d_in[4];
    const float* Wv   = (const float*)d_in[5];
    const float* Wo   = (const float*)d_in[6];
    float* out = (float*)d_out;

    // ws (bf16): Xb 16MB | Wqkv 12MB (q 8, k 2, v 2 contiguous) | Wob 8MB |
    //            Q 16MB | K 4MB | V^T 4MB
    char* ws = (char*)d_ws;
    bf16_t* Xb    = (bf16_t*)(ws);
    bf16_t* Wqkvb = (bf16_t*)(ws + (16u << 20));
    bf16_t* Wkb   = (bf16_t*)(ws + (24u << 20));
    bf16_t* Wvb   = (bf16_t*)(ws + (26u << 20));
    bf16_t* Wob   = (bf16_t*)(ws + (28u << 20));
    bf16_t* qbuf  = (bf16_t*)(ws + (36u << 20));
    bf16_t* kbuf  = (bf16_t*)(ws + (52u << 20));
    bf16_t* vtbuf = (bf16_t*)(ws + (56u << 20));

    dim3 blk(256, 1, 1);
    const int ncvt = N_X + 2 * N_WQ + 2 * N_WK;   // /2048 = 9216 blocks
    cvt_all<<<dim3(ncvt / 2048, 1, 1), blk, 0, stream>>>(
        X, Wq, Wk, Wv, Wo, Xb, Wqkvb, Wkb, Wvb, Wob);

    gemm_qkv<<<dim3(NQKV / 128, NTOK / 128), blk, 0, stream>>>(
        Xb, Wqkvb, qbuf, kbuf, vtbuf);
    rope_inplace<<<dim3((NTOK * 20 * 8) / 256), blk, 0, stream>>>(
        qbuf, kbuf, cosb, sinb);
    attn_fwd<<<dim3(512, 1, 1), dim3(512, 1, 1), 0, stream>>>(qbuf, kbuf, vtbuf);
    gemm_out<<<dim3(H_DIM / 128, NTOK / 128), blk, 0, stream>>>(qbuf, Wob, out);

    (void)in_sizes; (void)n_in; (void)out_size; (void)ws_size;
}

// Round 8
// 283.335 us; speedup vs baseline: 1.1101x; 1.0264x over previous
//
#include <hip/hip_runtime.h>
#include <hip/hip_bf16.h>
#include <stdint.h>

#define S_LEN 2048
#define H_DIM 2048
#define NHEADS 16
#define KVHEADS 4
#define HEAD_DIM 128
#define KV_DIM 512       // KVHEADS * HEAD_DIM
#define NTOK 4096        // B * S
#define NQKV 3072        // H_DIM + 2*KV_DIM

typedef __bf16 bf16_t;
typedef __bf16 bf16x8 __attribute__((ext_vector_type(8)));
typedef __bf16 bf16x4 __attribute__((ext_vector_type(4)));
typedef float f32x4 __attribute__((ext_vector_type(4)));

__device__ __forceinline__ f32x4 mfma16x16x32(bf16x8 a, bf16x8 b, f32x4 c) {
    return __builtin_amdgcn_mfma_f32_16x16x32_bf16(a, b, c, 0, 0, 0);
}

// async global->LDS, 16B per lane. LDS dest = wave-uniform base + lane*16;
// global address may be fully per-lane (scatter side is global).
__device__ __forceinline__ void gload_lds16(const bf16_t* g, bf16_t* l) {
    __builtin_amdgcn_global_load_lds(
        (__attribute__((address_space(1))) uint32_t*)(uintptr_t)g,
        (__attribute__((address_space(3))) uint32_t*)l, 16, 0, 0);
}

// Fused fp32->bf16 convert of all 5 tensors in one launch (8 elems/thread).
#define N_X  (NTOK * H_DIM)     // 8388608
#define N_WQ (H_DIM * H_DIM)    // 4194304
#define N_WK (KV_DIM * H_DIM)   // 1048576
__global__ __launch_bounds__(256) void cvt_all(const float* __restrict__ X,
                                               const float* __restrict__ Wq,
                                               const float* __restrict__ Wk,
                                               const float* __restrict__ Wv,
                                               const float* __restrict__ Wo,
                                               bf16_t* __restrict__ Xb,
                                               bf16_t* __restrict__ Wqb,
                                               bf16_t* __restrict__ Wkb,
                                               bf16_t* __restrict__ Wvb,
                                               bf16_t* __restrict__ Wob) {
    long i = (long)(blockIdx.x * 256 + threadIdx.x) * 8;
    const float* src;
    bf16_t* dst;
    if (i < N_X)                       { src = X;  dst = Xb; }
    else if ((i -= N_X) < N_WQ)        { src = Wq; dst = Wqb; }
    else if ((i -= N_WQ) < N_WK)       { src = Wk; dst = Wkb; }
    else if ((i -= N_WK) < N_WK)       { src = Wv; dst = Wvb; }
    else      { i -= N_WK;               src = Wo; dst = Wob; }
    const float4 a = *(const float4*)(src + i);
    const float4 b = *(const float4*)(src + i + 4);
    bf16x8 o;
    o[0] = (bf16_t)a.x; o[1] = (bf16_t)a.y; o[2] = (bf16_t)a.z; o[3] = (bf16_t)a.w;
    o[4] = (bf16_t)b.x; o[5] = (bf16_t)b.y; o[6] = (bf16_t)b.z; o[7] = (bf16_t)b.w;
    *(bf16x8*)(dst + i) = o;
}

// ---- shared GEMM main loop, used by both GEMM kernels ----
// m97 structure upgraded to BK=64: half the barrier/drain count of BK=32.
// LDS tiles [128][64] bf16 (16 KB each, 32 KB total). Staging goes through
// global_load_lds with a PRE-SWIZZLED global source column (the DMA writes
// LDS linearly): thread covers (row = c*32 + tid>>3, chunk = tid&7), global
// col chunk = (tid&7) ^ ((tid>>3)&7). Fragment reads then use
// chunk ^ (row&7) -> 2-way bank access (free) instead of 16-way at the
// naive 128 B row stride. Swizzle key is chunk-invariant (rows step by 32).
// Computes acc[4][4] for this thread's 64x64 wave tile at (m0+wm, n0+wn).
#define GEMM_BODY(A_, W_, K_)                                                  \
    __shared__ alignas(16) bf16_t As[128 * 64];                                \
    __shared__ alignas(16) bf16_t Bs[128 * 64];                                \
    const int tid  = threadIdx.x;                                              \
    const int wave = tid >> 6;                                                 \
    const int lane = tid & 63;                                                 \
    const int col  = lane & 15;                                                \
    const int quad = lane >> 4;                                                \
    const int m0 = blockIdx.y * 128;                                           \
    const int n0 = blockIdx.x * 128;                                           \
    const int wm = (wave >> 1) * 64;                                           \
    const int wn = (wave & 1) * 64;                                            \
    const int r0 = tid >> 3;             /* staging row in 32-row chunk */     \
    const int kk = ((tid & 7) ^ (r0 & 7)) * 8;  /* pre-swizzled k-chunk */     \
    const bf16_t* ab = (A_) + (size_t)(m0 + r0) * (K_) + kk;                   \
    const bf16_t* bb = (W_) + (size_t)(n0 + r0) * (K_) + kk;                   \
    bf16_t* lA = As + tid * 8;                                                 \
    bf16_t* lB = Bs + tid * 8;                                                 \
    const int swz = col & 7;                                                   \
    f32x4 acc[4][4];                                                           \
    _Pragma("unroll") for (int mi = 0; mi < 4; ++mi)                           \
        _Pragma("unroll") for (int ni = 0; ni < 4; ++ni)                       \
            acc[mi][ni] = (f32x4){0.f, 0.f, 0.f, 0.f};                         \
    for (int k0 = 0; k0 < (K_); k0 += 64) {                                    \
        __syncthreads();                                                       \
        _Pragma("unroll") for (int c = 0; c < 4; ++c) {                        \
            gload_lds16(ab + k0 + (size_t)(c * 32) * (K_), lA + c * 2048);     \
            gload_lds16(bb + k0 + (size_t)(c * 32) * (K_), lB + c * 2048);     \
        }                                                                      \
        __syncthreads();                                                       \
        _Pragma("unroll") for (int h = 0; h < 2; ++h) {                        \
            bf16x8 av[4], bv[4];                                               \
            _Pragma("unroll") for (int i = 0; i < 4; ++i) {                    \
                av[i] = *(const bf16x8*)(As + (wm + i * 16 + col) * 64 +       \
                                         (((h * 4 + quad) ^ swz) << 3));       \
                bv[i] = *(const bf16x8*)(Bs + (wn + i * 16 + col) * 64 +       \
                                         (((h * 4 + quad) ^ swz) << 3));       \
            }                                                                  \
            _Pragma("unroll") for (int mi = 0; mi < 4; ++mi)                   \
                _Pragma("unroll") for (int ni = 0; ni < 4; ++ni)               \
                    acc[mi][ni] = mfma16x16x32(av[mi], bv[ni], acc[mi][ni]);   \
        }                                                                      \
    }

// Fused QKV projection: C row-major views into qbuf [M][2048] (n<2048),
// kbuf [M][512] (2048<=n<2560), and V^T layout [b][kvh*128+d][s] (n>=2560).
__global__ __launch_bounds__(256) void gemm_qkv(const bf16_t* __restrict__ A,
                                                const bf16_t* __restrict__ W,
                                                bf16_t* __restrict__ qbuf,
                                                bf16_t* __restrict__ kbuf,
                                                bf16_t* __restrict__ vtbuf) {
    GEMM_BODY(A, W, H_DIM)
    const int ng = n0 + wn;   // 64-aligned; q/k/v boundaries are 64-aligned
    if (ng < H_DIM) {
#pragma unroll
        for (int mi = 0; mi < 4; ++mi)
#pragma unroll
            for (int ni = 0; ni < 4; ++ni)
#pragma unroll
                for (int r = 0; r < 4; ++r)
                    qbuf[(size_t)(m0 + wm + mi * 16 + quad * 4 + r) * H_DIM +
                         ng + ni * 16 + col] = (bf16_t)acc[mi][ni][r];
    } else if (ng < H_DIM + KV_DIM) {
#pragma unroll
        for (int mi = 0; mi < 4; ++mi)
#pragma unroll
            for (int ni = 0; ni < 4; ++ni)
#pragma unroll
                for (int r = 0; r < 4; ++r)
                    kbuf[(size_t)(m0 + wm + mi * 16 + quad * 4 + r) * KV_DIM +
                         ng - H_DIM + ni * 16 + col] = (bf16_t)acc[mi][ni][r];
    } else {
#pragma unroll
        for (int mi = 0; mi < 4; ++mi) {
            const int m = m0 + wm + mi * 16 + quad * 4;
#pragma unroll
            for (int ni = 0; ni < 4; ++ni) {
                const int nv = ng - (H_DIM + KV_DIM) + ni * 16 + col;
                const size_t off =
                    ((size_t)(m >> 11) * KV_DIM + nv) * S_LEN + (m & (S_LEN - 1));
                bf16x4 o;
#pragma unroll
                for (int r = 0; r < 4; ++r) o[r] = (bf16_t)acc[mi][ni][r];
                *(bf16x4*)(vtbuf + off) = o;
            }
        }
    }
}

// O projection: fp32 output.
__global__ __launch_bounds__(256) void gemm_out(const bf16_t* __restrict__ A,
                                                const bf16_t* __restrict__ W,
                                                float* __restrict__ C) {
    GEMM_BODY(A, W, H_DIM)
#pragma unroll
    for (int mi = 0; mi < 4; ++mi)
#pragma unroll
        for (int ni = 0; ni < 4; ++ni)
#pragma unroll
            for (int r = 0; r < 4; ++r)
                C[(size_t)(m0 + wm + mi * 16 + quad * 4 + r) * H_DIM +
                  n0 + wn + ni * 16 + col] = (float)acc[mi][ni][r];
}

// In-place RoPE on Q [NTOK][2048] (16 heads) and K [NTOK][512] (4 heads).
// Vectorized: 8 rotation pairs per thread (bf16x8 loads/stores, float4
// cos/sin). Q additionally pre-multiplied by scale*log2(e) so attn can use
// exp2 directly with no per-score multiply (attn overwrites Q with O before
// gemm_out reads it, so the scaling never leaks downstream).
#define QSCALE_LOG2E 0.12753102813264324f  // (1/sqrt(128)) * log2(e)
__global__ __launch_bounds__(256) void rope_inplace(bf16_t* __restrict__ Qb,
                                                    bf16_t* __restrict__ Kb,
                                                    const float* __restrict__ cosb,
                                                    const float* __restrict__ sinb) {
    const int idx  = blockIdx.x * 256 + threadIdx.x;  // NTOK*20*8 threads
    const int d8   = (idx & 7) * 8;
    const int rem  = idx >> 3;
    const int head = rem % 20;
    const int row  = rem / 20;
    const int s = row & (S_LEN - 1);
    const float4* cb = (const float4*)(cosb + s * HEAD_DIM);
    const float4* sb = (const float4*)(sinb + s * HEAD_DIM);
    float c0[8], s0[8], c1[8], s1[8];
    *(float4*)&c0[0] = cb[d8 >> 2];        *(float4*)&c0[4] = cb[(d8 >> 2) + 1];
    *(float4*)&s0[0] = sb[d8 >> 2];        *(float4*)&s0[4] = sb[(d8 >> 2) + 1];
    *(float4*)&c1[0] = cb[16 + (d8 >> 2)]; *(float4*)&c1[4] = cb[17 + (d8 >> 2)];
    *(float4*)&s1[0] = sb[16 + (d8 >> 2)]; *(float4*)&s1[4] = sb[17 + (d8 >> 2)];
    bf16_t* base = (head < NHEADS)
        ? Qb + (size_t)row * H_DIM + head * HEAD_DIM
        : Kb + (size_t)row * KV_DIM + (head - NHEADS) * HEAD_DIM;
    const float qs = (head < NHEADS) ? QSCALE_LOG2E : 1.0f;
    const bf16x8 lo = *(const bf16x8*)(base + d8);
    const bf16x8 hi = *(const bf16x8*)(base + d8 + 64);
    bf16x8 olo, ohi;
#pragma unroll
    for (int u = 0; u < 8; ++u) {
        const float lf = (float)lo[u];
        const float hf = (float)hi[u];
        olo[u] = (bf16_t)((lf * c0[u] - hf * s0[u]) * qs);
        ohi[u] = (bf16_t)((hf * c1[u] + lf * s1[u]) * qs);
    }
    *(bf16x8*)(base + d8)      = olo;
    *(bf16x8*)(base + d8 + 64) = ohi;
}

#define NEG_BIG (-1e30f)
#define TJ 64          // kv tile width
#define DEFER_THR 8.0f // defer-max threshold, log2 units (P bounded by 2^8)

// Flash attention, causal, transposed-score form.
// 8-wave (512-thread) blocks: waves 0-3 own q-tile 2i, waves 4-7 own q-tile
// 2i+1 (one GQA head each); both tiles need the SAME nsteps = i/2+1, so all
// 8 waves run uniform barriers while sharing one K/V staging stream.
// Complementary CU pairing: blocks id and id+256 co-locate on a CU under
// round-robin dispatch; i = (b? 63-j : j) makes each CU's two resident
// blocks' durations sum to exactly 33 steps.
// PV is K=32 MFMA with P^T staged through a DEDICATED wave-private LDS
// scratch Ps (8 x 2 KB). LDS total = 80 KB -> still exactly 2 blocks/CU,
// and no mid-step block barrier (Ps never aliases K/V): one __syncthreads
// per kv-step total, so waves slip independently through softmax+PV.
// DS ops complete in order per wave, so the lgkmcnt(0) before the P reads
// orders the preceding P writes; the Ks/Vs DMA-vs-read hazard is unchanged
// (top-of-step __syncthreads, DMA always targets buffer BUF^1).
// PV operand order mfma(vf, aP): D = O^T, layout O[q=col][d=dt*16+quad*4+r]
// -> alpha/l rescale is broadcast-free (indexed by q=col) and the epilogue
// stores are aligned bf16x4.
__global__ __launch_bounds__(512, 4) void attn_fwd(bf16_t* __restrict__ Q,
                                                   const bf16_t* __restrict__ Kb,
                                                   const bf16_t* __restrict__ Vt) {
    const int id   = blockIdx.x;       // 0..511
    const int jp   = id & 63;
    const int kvh  = (id >> 6) & 3;
    const int b    = id >> 8;
    const int i    = b ? (63 - jp) : jp;   // complementary pairing per CU
    const int tid  = threadIdx.x;
    const int wave = tid >> 6;
    const int lane = tid & 63;
    const int col  = lane & 15;
    const int quad = lane >> 4;
    const int grp  = wave >> 2;        // 0: tile 2i, 1: tile 2i+1
    const int h    = kvh * 4 + (wave & 3);
    const int q0   = (2 * i + grp) * 16;
    const int nsteps = (i >> 1) + 1;
    const int swz  = col & 7;          // read-side swizzle key

    // chunk-swizzled tiles: slot(j,c) = j*16 + (c^(j&7)) for K [64j][16c],
    // slot(d,cj) = d*8 + (cj^(d&7)) for V^T [128d][8cj]; elem addr = slot*8.
    __shared__ alignas(16) bf16_t Ks[2][TJ * HEAD_DIM];    // 16 KB each
    __shared__ alignas(16) bf16_t Vs[2][HEAD_DIM * TJ];    // 16 KB each
    __shared__ alignas(16) bf16_t Ps[8 * 1024];            // 16 KB, wave-priv

    const bf16_t* kbase = Kb + (size_t)(b * S_LEN) * KV_DIM + kvh * HEAD_DIM;
    const bf16_t* vtb   = Vt + (size_t)(b * KVHEADS + kvh) * HEAD_DIM * S_LEN;

    // per-lane global element offsets for the 2 K + 2 V staging DMAs
    int kgoff[2], vgoff[2];
#pragma unroll
    for (int im = 0; im < 2; ++im) {
        const int s = im * 512 + tid;
        const int jr = s >> 4, c = (s & 15) ^ (jr & 7);
        kgoff[im] = jr * KV_DIM + c * 8;
        const int d = s >> 3, cj = (s & 7) ^ (d & 7);
        vgoff[im] = d * S_LEN + cj * 8;
    }
    auto stage = [&](int buf, int j0) {
        const bf16_t* kb = kbase + (size_t)j0 * KV_DIM;
        const bf16_t* vb = vtb + j0;
#pragma unroll
        for (int im = 0; im < 2; ++im) {
            gload_lds16(kb + kgoff[im], &Ks[buf][(im * 512 + wave * 64) * 8]);
            gload_lds16(vb + vgoff[im], &Vs[buf][(im * 512 + wave * 64) * 8]);
        }
    };

    // hoisted fragment LDS byte addrs; tile index goes into imm offsets:
    // K frag (t,jc): kaddr[t] + jc*4096;  V frag (half,dt): vb0/1 + dt*2048
    int kaddr[4];
#pragma unroll
    for (int t = 0; t < 4; ++t)
        kaddr[t] = col * 256 + (((4 * t + quad) ^ swz) << 4);
    const int vb0 = col * 128 + ((quad ^ swz) << 4);
    const int vb1 = col * 128 + (((quad + 4) ^ swz) << 4);
    // P^T scratch offsets (wave-private 2 KB slice of Ps):
    // logical [q=col][j] row-major 128 B/row, XOR-swizzled by (col&7)<<4.
    int pwoff[4];
#pragma unroll
    for (int jc = 0; jc < 4; ++jc)
        pwoff[jc] = wave * 2048 +
                    ((col * 128 + jc * 32 + quad * 8) ^ (swz << 4));
    const int ap0 = wave * 2048 + ((col * 128 + quad * 16) ^ (swz << 4));
    const int ap1 = wave * 2048 + ((col * 128 + 64 + quad * 16) ^ (swz << 4));

// one kv-step with compile-time buffer index BUF (so the +16KiB buffer
// stride folds into ds_read offset immediates -> zero address VALU in loop)
#define ATTN_STEP(JT, BUF)                                                     \
    {                                                                          \
        const int jt_ = (JT);                                                  \
        const bool last_ = (jt_ == nsteps - 1);                                \
        __syncthreads();  /* vmcnt(0) drain: buf BUF staged; prev reads done */\
        if (!last_) stage((BUF) ^ 1, (jt_ + 1) * TJ);                          \
        const char* ksb = (const char*)Ks[(BUF)];                              \
        const char* vsb = (const char*)Vs[(BUF)];                              \
        char* pwb = (char*)Ps;          /* wave-private P^T scratch */         \
        f32x4 sc[4];                                                           \
        _Pragma("unroll") for (int jc = 0; jc < 4; ++jc)                       \
            sc[jc] = (f32x4){0.f, 0.f, 0.f, 0.f};                              \
        __builtin_amdgcn_s_setprio(1);                                         \
        _Pragma("unroll") for (int t = 0; t < 4; ++t)                          \
            _Pragma("unroll") for (int jc = 0; jc < 4; ++jc)                   \
                sc[jc] = mfma16x16x32(                                         \
                    *(const bf16x8*)(ksb + kaddr[t] + jc * 4096), qf[t],       \
                    sc[jc]);                                                   \
        __builtin_amdgcn_s_setprio(0);                                         \
        if (last_) {                                                           \
            const int j0_ = jt_ * TJ;                                          \
            const int q_ = q0 + col;                                           \
            _Pragma("unroll") for (int jc = 0; jc < 4; ++jc)                   \
                _Pragma("unroll") for (int r = 0; r < 4; ++r) {                \
                    const int j = j0_ + jc * 16 + quad * 4 + r;                \
                    if (j > q_) sc[jc][r] = NEG_BIG;                           \
                }                                                              \
        }                                                                      \
        float mx = sc[0][0];                                                   \
        _Pragma("unroll") for (int jc = 0; jc < 4; ++jc)                       \
            _Pragma("unroll") for (int r = 0; r < 4; ++r)                      \
                mx = fmaxf(mx, sc[jc][r]);                                     \
        /* per-lane partial max is a lower bound of the column max: if no  */  \
        /* lane exceeds m_i+THR, no column max does -> skip reduce+rescale */  \
        if (!__all(mx <= m_i + DEFER_THR)) {                                   \
            mx = fmaxf(mx, __shfl_xor(mx, 16));                                \
            mx = fmaxf(mx, __shfl_xor(mx, 32));                                \
            const float mn = fmaxf(m_i, mx);                                   \
            const float alpha = __builtin_amdgcn_exp2f(m_i - mn);              \
            m_i = mn;                                                          \
            l_i *= alpha;                                                      \
            _Pragma("unroll") for (int dt = 0; dt < 8; ++dt)                   \
                Oacc[dt] *= alpha;  /* O rows are q=col: no broadcast */       \
        }                                                                      \
        float sum = 0.f;                                                       \
        bf16x4 pb[4];                                                          \
        _Pragma("unroll") for (int jc = 0; jc < 4; ++jc)                       \
            _Pragma("unroll") for (int r = 0; r < 4; ++r) {                    \
                const float pe = __builtin_amdgcn_exp2f(sc[jc][r] - m_i);      \
                sum += pe;                                                     \
                pb[jc][r] = (bf16_t)pe;                                        \
            }                                                                  \
        _Pragma("unroll") for (int jc = 0; jc < 4; ++jc)                       \
            *(bf16x4*)(pwb + pwoff[jc]) = pb[jc];                              \
        sum += __shfl_xor(sum, 16);                                            \
        sum += __shfl_xor(sum, 32);                                            \
        l_i += sum;                                                            \
        asm volatile("s_waitcnt lgkmcnt(0)" ::: "memory");  /* P visible */    \
        const bf16x8 aP0 = *(const bf16x8*)(pwb + ap0);                        \
        const bf16x8 aP1 = *(const bf16x8*)(pwb + ap1);                        \
        __builtin_amdgcn_s_setprio(1);                                         \
        _Pragma("unroll") for (int dt = 0; dt < 8; ++dt) {                     \
            const bf16x8 vf0 = *(const bf16x8*)(vsb + vb0 + dt * 2048);        \
            const bf16x8 vf1 = *(const bf16x8*)(vsb + vb1 + dt * 2048);        \
            Oacc[dt] = mfma16x16x32(vf1, aP1,                                  \
                       mfma16x16x32(vf0, aP0, Oacc[dt]));                      \
        }                                                                      \
        __builtin_amdgcn_s_setprio(0);                                         \
    }

    stage(0, 0);

    bf16x8 qf[4];
    {
        const bf16_t* qp = Q + (size_t)(b * S_LEN + q0 + col) * H_DIM +
                           h * HEAD_DIM + quad * 8;
#pragma unroll
        for (int t = 0; t < 4; ++t) qf[t] = *(const bf16x8*)(qp + t * 32);
    }
    f32x4 Oacc[8];
#pragma unroll
    for (int dt = 0; dt < 8; ++dt) Oacc[dt] = (f32x4){0.f, 0.f, 0.f, 0.f};
    float m_i = NEG_BIG, l_i = 0.f;

    int jt = 0;
    while (true) {
        ATTN_STEP(jt, 0)
        if (++jt == nsteps) break;
        ATTN_STEP(jt, 1)
        if (++jt == nsteps) break;
    }

    // normalize and store in place: lane holds O[q=col][d=dt*16+quad*4+r],
    // l_i is indexed by q=col -> direct reciprocal, aligned 8B stores.
    {
        const float inv = 1.0f / l_i;
        const size_t rowoff =
            (size_t)(b * S_LEN + q0 + col) * H_DIM + h * HEAD_DIM + quad * 4;
#pragma unroll
        for (int dt = 0; dt < 8; ++dt) {
            bf16x4 o;
#pragma unroll
            for (int r = 0; r < 4; ++r) o[r] = (bf16_t)(Oacc[dt][r] * inv);
            *(bf16x4*)(Q + rowoff + dt * 16) = o;
        }
    }
#undef ATTN_STEP
}

extern "C" void kernel_launch(void* const* d_in, const int* in_sizes, int n_in,
                              void* d_out, int out_size, void* d_ws, size_t ws_size,
                              hipStream_t stream) {
    const float* X    = (const float*)d_in[0];
    const float* cosb = (const float*)d_in[1];
    const float* sinb = (const float*)d_in[2];
    const float* Wq   = (const float*)d_in[3];
    const float* Wk   = (const float*)d_in[4];
    const float* Wv   = (const float*)d_in[5];
    const float* Wo   = (const float*)d_in[6];
    float* out = (float*)d_out;

    // ws (bf16): Xb 16MB | Wqkv 12MB (q 8, k 2, v 2 contiguous) | Wob 8MB |
    //            Q 16MB | K 4MB | V^T 4MB
    char* ws = (char*)d_ws;
    bf16_t* Xb    = (bf16_t*)(ws);
    bf16_t* Wqkvb = (bf16_t*)(ws + (16u << 20));
    bf16_t* Wkb   = (bf16_t*)(ws + (24u << 20));
    bf16_t* Wvb   = (bf16_t*)(ws + (26u << 20));
    bf16_t* Wob   = (bf16_t*)(ws + (28u << 20));
    bf16_t* qbuf  = (bf16_t*)(ws + (36u << 20));
    bf16_t* kbuf  = (bf16_t*)(ws + (52u << 20));
    bf16_t* vtbuf = (bf16_t*)(ws + (56u << 20));

    dim3 blk(256, 1, 1);
    const int ncvt = N_X + 2 * N_WQ + 2 * N_WK;   // /2048 = 9216 blocks
    cvt_all<<<dim3(ncvt / 2048, 1, 1), blk, 0, stream>>>(
        X, Wq, Wk, Wv, Wo, Xb, Wqkvb, Wkb, Wvb, Wob);

    gemm_qkv<<<dim3(NQKV / 128, NTOK / 128), blk, 0, stream>>>(
        Xb, Wqkvb, qbuf, kbuf, vtbuf);
    rope_inplace<<<dim3((NTOK * 20 * 8) / 256), blk, 0, stream>>>(
        qbuf, kbuf, cosb, sinb);
    attn_fwd<<<dim3(512, 1, 1), dim3(512, 1, 1), 0, stream>>>(qbuf, kbuf, vtbuf);
    gemm_out<<<dim3(H_DIM / 128, NTOK / 128), blk, 0, stream>>>(qbuf, Wob, out);

    (void)in_sizes; (void)n_in; (void)out_size; (void)ws_size;
}

// Round 9
// 278.823 us; speedup vs baseline: 1.1280x; 1.0162x over previous
//
#include <hip/hip_runtime.h>
#include <hip/hip_bf16.h>
#include <stdint.h>

#define S_LEN 2048
#define H_DIM 2048
#define NHEADS 16
#define KVHEADS 4
#define HEAD_DIM 128
#define KV_DIM 512       // KVHEADS * HEAD_DIM
#define NTOK 4096        // B * S
#define NQKV 3072        // H_DIM + 2*KV_DIM

typedef __bf16 bf16_t;
typedef __bf16 bf16x8 __attribute__((ext_vector_type(8)));
typedef __bf16 bf16x4 __attribute__((ext_vector_type(4)));
typedef float f32x4 __attribute__((ext_vector_type(4)));

__device__ __forceinline__ f32x4 mfma16x16x32(bf16x8 a, bf16x8 b, f32x4 c) {
    return __builtin_amdgcn_mfma_f32_16x16x32_bf16(a, b, c, 0, 0, 0);
}

// async global->LDS, 16B per lane. LDS dest = wave-uniform base + lane*16;
// global address may be fully per-lane (scatter side is global).
__device__ __forceinline__ void gload_lds16(const bf16_t* g, bf16_t* l) {
    __builtin_amdgcn_global_load_lds(
        (__attribute__((address_space(1))) uint32_t*)(uintptr_t)g,
        (__attribute__((address_space(3))) uint32_t*)l, 16, 0, 0);
}

// Fused fp32->bf16 convert of all 5 tensors in one launch (8 elems/thread).
#define N_X  (NTOK * H_DIM)     // 8388608
#define N_WQ (H_DIM * H_DIM)    // 4194304
#define N_WK (KV_DIM * H_DIM)   // 1048576
__global__ __launch_bounds__(256) void cvt_all(const float* __restrict__ X,
                                               const float* __restrict__ Wq,
                                               const float* __restrict__ Wk,
                                               const float* __restrict__ Wv,
                                               const float* __restrict__ Wo,
                                               bf16_t* __restrict__ Xb,
                                               bf16_t* __restrict__ Wqb,
                                               bf16_t* __restrict__ Wkb,
                                               bf16_t* __restrict__ Wvb,
                                               bf16_t* __restrict__ Wob) {
    long i = (long)(blockIdx.x * 256 + threadIdx.x) * 8;
    const float* src;
    bf16_t* dst;
    if (i < N_X)                       { src = X;  dst = Xb; }
    else if ((i -= N_X) < N_WQ)        { src = Wq; dst = Wqb; }
    else if ((i -= N_WQ) < N_WK)       { src = Wk; dst = Wkb; }
    else if ((i -= N_WK) < N_WK)       { src = Wv; dst = Wvb; }
    else      { i -= N_WK;               src = Wo; dst = Wob; }
    const float4 a = *(const float4*)(src + i);
    const float4 b = *(const float4*)(src + i + 4);
    bf16x8 o;
    o[0] = (bf16_t)a.x; o[1] = (bf16_t)a.y; o[2] = (bf16_t)a.z; o[3] = (bf16_t)a.w;
    o[4] = (bf16_t)b.x; o[5] = (bf16_t)b.y; o[6] = (bf16_t)b.z; o[7] = (bf16_t)b.w;
    *(bf16x8*)(dst + i) = o;
}

// ---- GEMM main loop, BK=32 variant (m97 structure) ----
// Used by gemm_qkv (768 blocks, ~3/CU): at this concurrency the barrier
// drains are hidden by inter-block wave overlap, and BK=32 keeps occupancy
// high (round-7/8 A/B: BK=32 69.0 us vs BK=64 76.5 us on this grid).
#define GEMM_BODY32(A_, W_, K_)                                                \
    __shared__ alignas(16) bf16_t As[128 * 32];                                \
    __shared__ alignas(16) bf16_t Bs[128 * 32];                                \
    const int tid  = threadIdx.x;                                              \
    const int wave = tid >> 6;                                                 \
    const int lane = tid & 63;                                                 \
    const int col  = lane & 15;                                                \
    const int quad = lane >> 4;                                                \
    const int m0 = blockIdx.y * 128;                                           \
    const int n0 = blockIdx.x * 128;                                           \
    const int wm = (wave >> 1) * 64;                                           \
    const int wn = (wave & 1) * 64;                                            \
    const int r0 = tid >> 2;                                                   \
    const int kk = (tid & 3) * 8;                                              \
    const bf16_t* a0 = (A_) + (size_t)(m0 + r0) * (K_) + kk;                   \
    const bf16_t* a1 = a0 + (size_t)64 * (K_);                                 \
    const bf16_t* b0 = (W_) + (size_t)(n0 + r0) * (K_) + kk;                   \
    const bf16_t* b1 = b0 + (size_t)64 * (K_);                                 \
    bf16_t* lA0 = As + tid * 8;                                                \
    bf16_t* lA1 = As + 2048 + tid * 8;                                         \
    bf16_t* lB0 = Bs + tid * 8;                                                \
    bf16_t* lB1 = Bs + 2048 + tid * 8;                                         \
    f32x4 acc[4][4];                                                           \
    _Pragma("unroll") for (int mi = 0; mi < 4; ++mi)                           \
        _Pragma("unroll") for (int ni = 0; ni < 4; ++ni)                       \
            acc[mi][ni] = (f32x4){0.f, 0.f, 0.f, 0.f};                         \
    for (int k0 = 0; k0 < (K_); k0 += 32) {                                    \
        __syncthreads();                                                       \
        gload_lds16(a0 + k0, lA0);                                             \
        gload_lds16(a1 + k0, lA1);                                             \
        gload_lds16(b0 + k0, lB0);                                             \
        gload_lds16(b1 + k0, lB1);                                             \
        __syncthreads();                                                       \
        bf16x8 av[4], bv[4];                                                   \
        _Pragma("unroll") for (int i = 0; i < 4; ++i) {                        \
            av[i] = *(const bf16x8*)(As + (wm + i * 16 + col) * 32 + quad * 8);\
            bv[i] = *(const bf16x8*)(Bs + (wn + i * 16 + col) * 32 + quad * 8);\
        }                                                                      \
        _Pragma("unroll") for (int mi = 0; mi < 4; ++mi)                       \
            _Pragma("unroll") for (int ni = 0; ni < 4; ++ni)                   \
                acc[mi][ni] = mfma16x16x32(av[mi], bv[ni], acc[mi][ni]);       \
    }

// ---- GEMM main loop, BK=64 variant with XOR-swizzled staging ----
// Used by gemm_out (128 blocks, ~0.5/CU): no neighbor waves to hide the
// per-step vmcnt drain, so halving the barrier count pays (round-7/8 A/B:
// ~ -15 us on this grid). Reads are conflict-free via both-sides swizzle.
#define GEMM_BODY64(A_, W_, K_)                                                \
    __shared__ alignas(16) bf16_t As[128 * 64];                                \
    __shared__ alignas(16) bf16_t Bs[128 * 64];                                \
    const int tid  = threadIdx.x;                                              \
    const int wave = tid >> 6;                                                 \
    const int lane = tid & 63;                                                 \
    const int col  = lane & 15;                                                \
    const int quad = lane >> 4;                                                \
    const int m0 = blockIdx.y * 128;                                           \
    const int n0 = blockIdx.x * 128;                                           \
    const int wm = (wave >> 1) * 64;                                           \
    const int wn = (wave & 1) * 64;                                            \
    const int r0 = tid >> 3;             /* staging row in 32-row chunk */     \
    const int kk = ((tid & 7) ^ (r0 & 7)) * 8;  /* pre-swizzled k-chunk */     \
    const bf16_t* ab = (A_) + (size_t)(m0 + r0) * (K_) + kk;                   \
    const bf16_t* bb = (W_) + (size_t)(n0 + r0) * (K_) + kk;                   \
    bf16_t* lA = As + tid * 8;                                                 \
    bf16_t* lB = Bs + tid * 8;                                                 \
    const int swz = col & 7;                                                   \
    f32x4 acc[4][4];                                                           \
    _Pragma("unroll") for (int mi = 0; mi < 4; ++mi)                           \
        _Pragma("unroll") for (int ni = 0; ni < 4; ++ni)                       \
            acc[mi][ni] = (f32x4){0.f, 0.f, 0.f, 0.f};                         \
    for (int k0 = 0; k0 < (K_); k0 += 64) {                                    \
        __syncthreads();                                                       \
        _Pragma("unroll") for (int c = 0; c < 4; ++c) {                        \
            gload_lds16(ab + k0 + (size_t)(c * 32) * (K_), lA + c * 2048);     \
            gload_lds16(bb + k0 + (size_t)(c * 32) * (K_), lB + c * 2048);     \
        }                                                                      \
        __syncthreads();                                                       \
        _Pragma("unroll") for (int h = 0; h < 2; ++h) {                        \
            bf16x8 av[4], bv[4];                                               \
            _Pragma("unroll") for (int i = 0; i < 4; ++i) {                    \
                av[i] = *(const bf16x8*)(As + (wm + i * 16 + col) * 64 +       \
                                         (((h * 4 + quad) ^ swz) << 3));       \
                bv[i] = *(const bf16x8*)(Bs + (wn + i * 16 + col) * 64 +       \
                                         (((h * 4 + quad) ^ swz) << 3));       \
            }                                                                  \
            _Pragma("unroll") for (int mi = 0; mi < 4; ++mi)                   \
                _Pragma("unroll") for (int ni = 0; ni < 4; ++ni)               \
                    acc[mi][ni] = mfma16x16x32(av[mi], bv[ni], acc[mi][ni]);   \
        }                                                                      \
    }

// Fused QKV projection: C row-major views into qbuf [M][2048] (n<2048),
// kbuf [M][512] (2048<=n<2560), and V^T layout [b][kvh*128+d][s] (n>=2560).
__global__ __launch_bounds__(256) void gemm_qkv(const bf16_t* __restrict__ A,
                                                const bf16_t* __restrict__ W,
                                                bf16_t* __restrict__ qbuf,
                                                bf16_t* __restrict__ kbuf,
                                                bf16_t* __restrict__ vtbuf) {
    GEMM_BODY32(A, W, H_DIM)
    const int ng = n0 + wn;   // 64-aligned; q/k/v boundaries are 64-aligned
    if (ng < H_DIM) {
#pragma unroll
        for (int mi = 0; mi < 4; ++mi)
#pragma unroll
            for (int ni = 0; ni < 4; ++ni)
#pragma unroll
                for (int r = 0; r < 4; ++r)
                    qbuf[(size_t)(m0 + wm + mi * 16 + quad * 4 + r) * H_DIM +
                         ng + ni * 16 + col] = (bf16_t)acc[mi][ni][r];
    } else if (ng < H_DIM + KV_DIM) {
#pragma unroll
        for (int mi = 0; mi < 4; ++mi)
#pragma unroll
            for (int ni = 0; ni < 4; ++ni)
#pragma unroll
                for (int r = 0; r < 4; ++r)
                    kbuf[(size_t)(m0 + wm + mi * 16 + quad * 4 + r) * KV_DIM +
                         ng - H_DIM + ni * 16 + col] = (bf16_t)acc[mi][ni][r];
    } else {
#pragma unroll
        for (int mi = 0; mi < 4; ++mi) {
            const int m = m0 + wm + mi * 16 + quad * 4;
#pragma unroll
            for (int ni = 0; ni < 4; ++ni) {
                const int nv = ng - (H_DIM + KV_DIM) + ni * 16 + col;
                const size_t off =
                    ((size_t)(m >> 11) * KV_DIM + nv) * S_LEN + (m & (S_LEN - 1));
                bf16x4 o;
#pragma unroll
                for (int r = 0; r < 4; ++r) o[r] = (bf16_t)acc[mi][ni][r];
                *(bf16x4*)(vtbuf + off) = o;
            }
        }
    }
}

// O projection: fp32 output.
__global__ __launch_bounds__(256) void gemm_out(const bf16_t* __restrict__ A,
                                                const bf16_t* __restrict__ W,
                                                float* __restrict__ C) {
    GEMM_BODY64(A, W, H_DIM)
#pragma unroll
    for (int mi = 0; mi < 4; ++mi)
#pragma unroll
        for (int ni = 0; ni < 4; ++ni)
#pragma unroll
            for (int r = 0; r < 4; ++r)
                C[(size_t)(m0 + wm + mi * 16 + quad * 4 + r) * H_DIM +
                  n0 + wn + ni * 16 + col] = (float)acc[mi][ni][r];
}

// In-place RoPE on Q [NTOK][2048] (16 heads) and K [NTOK][512] (4 heads).
// Vectorized: 8 rotation pairs per thread (bf16x8 loads/stores, float4
// cos/sin). Q additionally pre-multiplied by scale*log2(e) so attn can use
// exp2 directly with no per-score multiply (attn overwrites Q with O before
// gemm_out reads it, so the scaling never leaks downstream).
#define QSCALE_LOG2E 0.12753102813264324f  // (1/sqrt(128)) * log2(e)
__global__ __launch_bounds__(256) void rope_inplace(bf16_t* __restrict__ Qb,
                                                    bf16_t* __restrict__ Kb,
                                                    const float* __restrict__ cosb,
                                                    const float* __restrict__ sinb) {
    const int idx  = blockIdx.x * 256 + threadIdx.x;  // NTOK*20*8 threads
    const int d8   = (idx & 7) * 8;
    const int rem  = idx >> 3;
    const int head = rem % 20;
    const int row  = rem / 20;
    const int s = row & (S_LEN - 1);
    const float4* cb = (const float4*)(cosb + s * HEAD_DIM);
    const float4* sb = (const float4*)(sinb + s * HEAD_DIM);
    float c0[8], s0[8], c1[8], s1[8];
    *(float4*)&c0[0] = cb[d8 >> 2];        *(float4*)&c0[4] = cb[(d8 >> 2) + 1];
    *(float4*)&s0[0] = sb[d8 >> 2];        *(float4*)&s0[4] = sb[(d8 >> 2) + 1];
    *(float4*)&c1[0] = cb[16 + (d8 >> 2)]; *(float4*)&c1[4] = cb[17 + (d8 >> 2)];
    *(float4*)&s1[0] = sb[16 + (d8 >> 2)]; *(float4*)&s1[4] = sb[17 + (d8 >> 2)];
    bf16_t* base = (head < NHEADS)
        ? Qb + (size_t)row * H_DIM + head * HEAD_DIM
        : Kb + (size_t)row * KV_DIM + (head - NHEADS) * HEAD_DIM;
    const float qs = (head < NHEADS) ? QSCALE_LOG2E : 1.0f;
    const bf16x8 lo = *(const bf16x8*)(base + d8);
    const bf16x8 hi = *(const bf16x8*)(base + d8 + 64);
    bf16x8 olo, ohi;
#pragma unroll
    for (int u = 0; u < 8; ++u) {
        const float lf = (float)lo[u];
        const float hf = (float)hi[u];
        olo[u] = (bf16_t)((lf * c0[u] - hf * s0[u]) * qs);
        ohi[u] = (bf16_t)((hf * c1[u] + lf * s1[u]) * qs);
    }
    *(bf16x8*)(base + d8)      = olo;
    *(bf16x8*)(base + d8 + 64) = ohi;
}

#define NEG_BIG (-1e30f)
#define TJ 64          // kv tile width
#define DEFER_THR 8.0f // defer-max threshold, log2 units (P bounded by 2^8)

// Flash attention, causal, transposed-score form.
// 8-wave (512-thread) blocks: waves 0-3 own q-tile 2i, waves 4-7 own q-tile
// 2i+1 (one GQA head each); both tiles need the SAME nsteps = i/2+1, so all
// 8 waves run uniform barriers while sharing one K/V staging stream.
// Complementary CU pairing: blocks id and id+256 co-locate on a CU under
// round-robin dispatch; i = (b? 63-j : j) makes each CU's two resident
// blocks' durations sum to exactly 33 steps.
// PV is K=32 MFMA with P^T staged through a DEDICATED wave-private LDS
// scratch Ps (8 x 2 KB). LDS total = 80 KB -> still exactly 2 blocks/CU,
// and no mid-step block barrier (Ps never aliases K/V): one __syncthreads
// per kv-step total, so waves slip independently through softmax+PV.
// DS ops complete in order per wave, so the lgkmcnt(0) before the P reads
// orders the preceding P writes; the Ks/Vs DMA-vs-read hazard is unchanged
// (top-of-step __syncthreads, DMA always targets buffer BUF^1).
// PV operand order mfma(vf, aP): D = O^T, layout O[q=col][d=dt*16+quad*4+r]
// -> alpha/l rescale is broadcast-free (indexed by q=col) and the epilogue
// stores are aligned bf16x4.
__global__ __launch_bounds__(512, 4) void attn_fwd(bf16_t* __restrict__ Q,
                                                   const bf16_t* __restrict__ Kb,
                                                   const bf16_t* __restrict__ Vt) {
    const int id   = blockIdx.x;       // 0..511
    const int jp   = id & 63;
    const int kvh  = (id >> 6) & 3;
    const int b    = id >> 8;
    const int i    = b ? (63 - jp) : jp;   // complementary pairing per CU
    const int tid  = threadIdx.x;
    const int wave = tid >> 6;
    const int lane = tid & 63;
    const int col  = lane & 15;
    const int quad = lane >> 4;
    const int grp  = wave >> 2;        // 0: tile 2i, 1: tile 2i+1
    const int h    = kvh * 4 + (wave & 3);
    const int q0   = (2 * i + grp) * 16;
    const int nsteps = (i >> 1) + 1;
    const int swz  = col & 7;          // read-side swizzle key

    // chunk-swizzled tiles: slot(j,c) = j*16 + (c^(j&7)) for K [64j][16c],
    // slot(d,cj) = d*8 + (cj^(d&7)) for V^T [128d][8cj]; elem addr = slot*8.
    __shared__ alignas(16) bf16_t Ks[2][TJ * HEAD_DIM];    // 16 KB each
    __shared__ alignas(16) bf16_t Vs[2][HEAD_DIM * TJ];    // 16 KB each
    __shared__ alignas(16) bf16_t Ps[8 * 1024];            // 16 KB, wave-priv

    const bf16_t* kbase = Kb + (size_t)(b * S_LEN) * KV_DIM + kvh * HEAD_DIM;
    const bf16_t* vtb   = Vt + (size_t)(b * KVHEADS + kvh) * HEAD_DIM * S_LEN;

    // per-lane global element offsets for the 2 K + 2 V staging DMAs
    int kgoff[2], vgoff[2];
#pragma unroll
    for (int im = 0; im < 2; ++im) {
        const int s = im * 512 + tid;
        const int jr = s >> 4, c = (s & 15) ^ (jr & 7);
        kgoff[im] = jr * KV_DIM + c * 8;
        const int d = s >> 3, cj = (s & 7) ^ (d & 7);
        vgoff[im] = d * S_LEN + cj * 8;
    }
    auto stage = [&](int buf, int j0) {
        const bf16_t* kb = kbase + (size_t)j0 * KV_DIM;
        const bf16_t* vb = vtb + j0;
#pragma unroll
        for (int im = 0; im < 2; ++im) {
            gload_lds16(kb + kgoff[im], &Ks[buf][(im * 512 + wave * 64) * 8]);
            gload_lds16(vb + vgoff[im], &Vs[buf][(im * 512 + wave * 64) * 8]);
        }
    };

    // hoisted fragment LDS byte addrs; tile index goes into imm offsets:
    // K frag (t,jc): kaddr[t] + jc*4096;  V frag (half,dt): vb0/1 + dt*2048
    int kaddr[4];
#pragma unroll
    for (int t = 0; t < 4; ++t)
        kaddr[t] = col * 256 + (((4 * t + quad) ^ swz) << 4);
    const int vb0 = col * 128 + ((quad ^ swz) << 4);
    const int vb1 = col * 128 + (((quad + 4) ^ swz) << 4);
    // P^T scratch offsets (wave-private 2 KB slice of Ps):
    // logical [q=col][j] row-major 128 B/row, XOR-swizzled by (col&7)<<4.
    int pwoff[4];
#pragma unroll
    for (int jc = 0; jc < 4; ++jc)
        pwoff[jc] = wave * 2048 +
                    ((col * 128 + jc * 32 + quad * 8) ^ (swz << 4));
    const int ap0 = wave * 2048 + ((col * 128 + quad * 16) ^ (swz << 4));
    const int ap1 = wave * 2048 + ((col * 128 + 64 + quad * 16) ^ (swz << 4));

// one kv-step with compile-time buffer index BUF (so the +16KiB buffer
// stride folds into ds_read offset immediates -> zero address VALU in loop)
#define ATTN_STEP(JT, BUF)                                                     \
    {                                                                          \
        const int jt_ = (JT);                                                  \
        const bool last_ = (jt_ == nsteps - 1);                                \
        __syncthreads();  /* vmcnt(0) drain: buf BUF staged; prev reads done */\
        if (!last_) stage((BUF) ^ 1, (jt_ + 1) * TJ);                          \
        const char* ksb = (const char*)Ks[(BUF)];                              \
        const char* vsb = (const char*)Vs[(BUF)];                              \
        char* pwb = (char*)Ps;          /* wave-private P^T scratch */         \
        f32x4 sc[4];                                                           \
        _Pragma("unroll") for (int jc = 0; jc < 4; ++jc)                       \
            sc[jc] = (f32x4){0.f, 0.f, 0.f, 0.f};                              \
        __builtin_amdgcn_s_setprio(1);                                         \
        _Pragma("unroll") for (int t = 0; t < 4; ++t)                          \
            _Pragma("unroll") for (int jc = 0; jc < 4; ++jc)                   \
                sc[jc] = mfma16x16x32(                                         \
                    *(const bf16x8*)(ksb + kaddr[t] + jc * 4096), qf[t],       \
                    sc[jc]);                                                   \
        __builtin_amdgcn_s_setprio(0);                                         \
        if (last_) {                                                           \
            const int j0_ = jt_ * TJ;                                          \
            const int q_ = q0 + col;                                           \
            _Pragma("unroll") for (int jc = 0; jc < 4; ++jc)                   \
                _Pragma("unroll") for (int r = 0; r < 4; ++r) {                \
                    const int j = j0_ + jc * 16 + quad * 4 + r;                \
                    if (j > q_) sc[jc][r] = NEG_BIG;                           \
                }                                                              \
        }                                                                      \
        float mx = sc[0][0];                                                   \
        _Pragma("unroll") for (int jc = 0; jc < 4; ++jc)                       \
            _Pragma("unroll") for (int r = 0; r < 4; ++r)                      \
                mx = fmaxf(mx, sc[jc][r]);                                     \
        /* per-lane partial max is a lower bound of the column max: if no  */  \
        /* lane exceeds m_i+THR, no column max does -> skip reduce+rescale */  \
        if (!__all(mx <= m_i + DEFER_THR)) {                                   \
            mx = fmaxf(mx, __shfl_xor(mx, 16));                                \
            mx = fmaxf(mx, __shfl_xor(mx, 32));                                \
            const float mn = fmaxf(m_i, mx);                                   \
            const float alpha = __builtin_amdgcn_exp2f(m_i - mn);              \
            m_i = mn;                                                          \
            l_i *= alpha;                                                      \
            _Pragma("unroll") for (int dt = 0; dt < 8; ++dt)                   \
                Oacc[dt] *= alpha;  /* O rows are q=col: no broadcast */       \
        }                                                                      \
        float sum = 0.f;                                                       \
        bf16x4 pb[4];                                                          \
        _Pragma("unroll") for (int jc = 0; jc < 4; ++jc)                       \
            _Pragma("unroll") for (int r = 0; r < 4; ++r) {                    \
                const float pe = __builtin_amdgcn_exp2f(sc[jc][r] - m_i);      \
                sum += pe;                                                     \
                pb[jc][r] = (bf16_t)pe;                                        \
            }                                                                  \
        _Pragma("unroll") for (int jc = 0; jc < 4; ++jc)                       \
            *(bf16x4*)(pwb + pwoff[jc]) = pb[jc];                              \
        sum += __shfl_xor(sum, 16);                                            \
        sum += __shfl_xor(sum, 32);                                            \
        l_i += sum;                                                            \
        asm volatile("s_waitcnt lgkmcnt(0)" ::: "memory");  /* P visible */    \
        const bf16x8 aP0 = *(const bf16x8*)(pwb + ap0);                        \
        const bf16x8 aP1 = *(const bf16x8*)(pwb + ap1);                        \
        __builtin_amdgcn_s_setprio(1);                                         \
        _Pragma("unroll") for (int dt = 0; dt < 8; ++dt) {                     \
            const bf16x8 vf0 = *(const bf16x8*)(vsb + vb0 + dt * 2048);        \
            const bf16x8 vf1 = *(const bf16x8*)(vsb + vb1 + dt * 2048);        \
            Oacc[dt] = mfma16x16x32(vf1, aP1,                                  \
                       mfma16x16x32(vf0, aP0, Oacc[dt]));                      \
        }                                                                      \
        __builtin_amdgcn_s_setprio(0);                                         \
    }

    stage(0, 0);

    bf16x8 qf[4];
    {
        const bf16_t* qp = Q + (size_t)(b * S_LEN + q0 + col) * H_DIM +
                           h * HEAD_DIM + quad * 8;
#pragma unroll
        for (int t = 0; t < 4; ++t) qf[t] = *(const bf16x8*)(qp + t * 32);
    }
    f32x4 Oacc[8];
#pragma unroll
    for (int dt = 0; dt < 8; ++dt) Oacc[dt] = (f32x4){0.f, 0.f, 0.f, 0.f};
    float m_i = NEG_BIG, l_i = 0.f;

    int jt = 0;
    while (true) {
        ATTN_STEP(jt, 0)
        if (++jt == nsteps) break;
        ATTN_STEP(jt, 1)
        if (++jt == nsteps) break;
    }

    // normalize and store in place: lane holds O[q=col][d=dt*16+quad*4+r],
    // l_i is indexed by q=col -> direct reciprocal, aligned 8B stores.
    {
        const float inv = 1.0f / l_i;
        const size_t rowoff =
            (size_t)(b * S_LEN + q0 + col) * H_DIM + h * HEAD_DIM + quad * 4;
#pragma unroll
        for (int dt = 0; dt < 8; ++dt) {
            bf16x4 o;
#pragma unroll
            for (int r = 0; r < 4; ++r) o[r] = (bf16_t)(Oacc[dt][r] * inv);
            *(bf16x4*)(Q + rowoff + dt * 16) = o;
        }
    }
#undef ATTN_STEP
}

extern "C" void kernel_launch(void* const* d_in, const int* in_sizes, int n_in,
                              void* d_out, int out_size, void* d_ws, size_t ws_size,
                              hipStream_t stream) {
    const float* X    = (const float*)d_in[0];
    const float* cosb = (const float*)d_in[1];
    const float* sinb = (const float*)d_in[2];
    const float* Wq   = (const float*)d_in[3];
    const float* Wk   = (const float*)d_in[4];
    const float* Wv   = (const float*)d_in[5];
    const float* Wo   = (const float*)d_in[6];
    float* out = (float*)d_out;

    // ws (bf16): Xb 16MB | Wqkv 12MB (q 8, k 2, v 2 contiguous) | Wob 8MB |
    //            Q 16MB | K 4MB | V^T 4MB
    char* ws = (char*)d_ws;
    bf16_t* Xb    = (bf16_t*)(ws);
    bf16_t* Wqkvb = (bf16_t*)(ws + (16u << 20));
    bf16_t* Wkb   = (bf16_t*)(ws + (24u << 20));
    bf16_t* Wvb   = (bf16_t*)(ws + (26u << 20));
    bf16_t* Wob   = (bf16_t*)(ws + (28u << 20));
    bf16_t* qbuf  = (bf16_t*)(ws + (36u << 20));
    bf16_t* kbuf  = (bf16_t*)(ws + (52u << 20));
    bf16_t* vtbuf = (bf16_t*)(ws + (56u << 20));

    dim3 blk(256, 1, 1);
    const int ncvt = N_X + 2 * N_WQ + 2 * N_WK;   // /2048 = 9216 blocks
    cvt_all<<<dim3(ncvt / 2048, 1, 1), blk, 0, stream>>>(
        X, Wq, Wk, Wv, Wo, Xb, Wqkvb, Wkb, Wvb, Wob);

    gemm_qkv<<<dim3(NQKV / 128, NTOK / 128), blk, 0, stream>>>(
        Xb, Wqkvb, qbuf, kbuf, vtbuf);
    rope_inplace<<<dim3((NTOK * 20 * 8) / 256), blk, 0, stream>>>(
        qbuf, kbuf, cosb, sinb);
    attn_fwd<<<dim3(512, 1, 1), dim3(512, 1, 1), 0, stream>>>(qbuf, kbuf, vtbuf);
    gemm_out<<<dim3(H_DIM / 128, NTOK / 128), blk, 0, stream>>>(qbuf, Wob, out);

    (void)in_sizes; (void)n_in; (void)out_size; (void)ws_size;
}